// Round 1
// baseline (1065.146 us; speedup 1.0000x reference)
//
#include <hip/hip_runtime.h>

// ContinuousNormalizingFlow: B=32768 rows, D=8, H=64, 100 Euler steps.
// R17: occupancy-doubling pass. R16 was structurally 2 waves/SIMD
// (2048 waves = 32768 rows / 16 rows-per-wave), measured VALUBusy=63%,
// MfmaUtil=27% -> VALU/trans pipe had ~37% idle issue slots from
// MFMA<->VALU dependency bubbles that 2 waves can't cover.
// Change: 8 rows per wave, duplicated into both halves of the 16-wide
// MFMA B tile (lane c holds row row0+(c&7)). Total VALU/trans work is
// unchanged; MFMA instruction count doubles (27%->~50%, paid from the
// idle matrix pipe); resident waves double to 4/SIMD (launch_bounds
// (256,4), 124 VGPR fits the 128 cap). Everything else is R16 exactly.

#define TSCALE 2.885390081777926815f // 2*log2(e)

// tanh from PRE-SCALED z (z = 2*log2e*x): 1 - 2/(2^z + 1). inf-safe.
__device__ __forceinline__ float ftanh_s(float z) {
    float e = __builtin_amdgcn_exp2f(z);
    float r = __builtin_amdgcn_rcpf(e + 1.0f);
    return fmaf(-2.0f, r, 1.0f);
}

typedef __attribute__((ext_vector_type(8))) _Float16 v8h; // 8 f16 (4 VGPRs)
typedef __attribute__((ext_vector_type(2))) __fp16 v2fp; // cvt_pkrtz result
typedef __attribute__((ext_vector_type(4))) float v4f;   // MFMA C/D
typedef __attribute__((ext_vector_type(2))) float v2f;   // packed fp32 pair

union FragU {
    v8h h;
    unsigned u[4];
};

// f16 pair pack: single v_cvt_pkrtz_f16_f32. a -> low half.
__device__ __forceinline__ unsigned pk16(float a, float b) {
    v2fp t = __builtin_amdgcn_cvt_pkrtz(a, b);
    return __builtin_bit_cast(unsigned, t);
}
__device__ __forceinline__ unsigned pk16v(v2f v) { return pk16(v.x, v.y); }

// K-permutation for W2/W3 frags: slot (ks,q,jj) <- physical j.
__device__ __forceinline__ int physj(int ks, int q, int jj) {
    return 16 * (ks + 2 * (jj >> 2)) + 4 * q + (jj & 3);
}

// Rename C-fragment packs (ph[4]: per-mt {r01,r23}) into the B-frag pair.
__device__ __forceinline__ void rename(const uint2 ph[4], FragU bh[2]) {
#pragma unroll
    for (int ks = 0; ks < 2; ++ks) {
        bh[ks].u[0] = ph[ks].x;
        bh[ks].u[1] = ph[ks].y;
        bh[ks].u[2] = ph[ks + 2].x;
        bh[ks].u[3] = ph[ks + 2].y;
    }
}

__global__ __launch_bounds__(256, 4) void cnf_fused(
    const float* __restrict__ x0, const float* __restrict__ W1,
    const float* __restrict__ b1, const float* __restrict__ W2,
    const float* __restrict__ b2, const float* __restrict__ W3,
    const float* __restrict__ b3, const int* __restrict__ nsp,
    float* __restrict__ out, int rows) {
    const int tid = threadIdx.x;
    const int w = tid >> 6;
    const int lane = tid & 63;
    const int c = lane & 15;
    const int q = lane >> 4;
    // 8 rows per wave; lanes c and c+8 duplicate the same row so all 16
    // B-tile columns stay finite (inf/nan-free) at zero extra VALU cost.
    const int row0 = blockIdx.x * 32 + w * 8;
    const int myrow = row0 + (c & 7);

    const int n = *nsp;
    const float dt = 1.0f / (float)n;

    // ---- A1 (x TSCALE): [x;t;1] layout. q0 jj0-3 = W1[:,0:4], q0 jj4 =
    // W1[:,8] (t), q0 jj5 = b1, q1 jj0-3 = W1[:,4:8], all else 0. ----
    FragU a1[4];
#pragma unroll
    for (int mt = 0; mt < 4; ++mt) {
        const int m = 16 * mt + c;
        float f[8] = {0.f, 0.f, 0.f, 0.f, 0.f, 0.f, 0.f, 0.f};
        if (q == 0) {
#pragma unroll
            for (int jj = 0; jj < 4; ++jj) f[jj] = TSCALE * W1[m * 9 + jj];
            f[4] = TSCALE * W1[m * 9 + 8];
            f[5] = TSCALE * b1[m];
        } else if (q == 1) {
#pragma unroll
            for (int jj = 0; jj < 4; ++jj) f[jj] = TSCALE * W1[m * 9 + 4 + jj];
        }
#pragma unroll
        for (int p = 0; p < 4; ++p) a1[mt].u[p] = pk16(f[2 * p], f[2 * p + 1]);
    }
    // ---- A2 (x TSCALE) K-perm; a2g = w3c[m]*W2*w1r[h]; a2d = W2*(dt*w1t[h]).
    // w1r[h] = sum_k W1[h][0:8]; w3c[m] = sum_d W3[d][m] — computed inline
    // (L2-broadcast loads; prep kernel eliminated). ----
    FragU a2[4][2], a2g[4][2], a2d[4][2];
#pragma unroll
    for (int mt = 0; mt < 4; ++mt) {
        const int m = 16 * mt + c;
        float w3cm = 0.f;
#pragma unroll
        for (int d = 0; d < 8; ++d) w3cm += W3[d * 64 + m];
#pragma unroll
        for (int ks = 0; ks < 2; ++ks) {
            float f[8], fg[8], fd[8];
#pragma unroll
            for (int jj = 0; jj < 8; ++jj) {
                const int pj = physj(ks, q, jj);
                const float wv = W2[m * 64 + pj];
                float w1r = 0.f;
#pragma unroll
                for (int k = 0; k < 8; ++k) w1r += W1[pj * 9 + k];
                f[jj] = TSCALE * wv;
                fg[jj] = w3cm * wv * w1r;
                fd[jj] = wv * (dt * W1[pj * 9 + 8]);
            }
#pragma unroll
            for (int p = 0; p < 4; ++p) {
                a2[mt][ks].u[p] = pk16(f[2 * p], f[2 * p + 1]);
                a2g[mt][ks].u[p] = pk16(fg[2 * p], fg[2 * p + 1]);
                a2d[mt][ks].u[p] = pk16(fd[2 * p], fd[2 * p + 1]);
            }
        }
    }
    // ---- A3: W3 rows duplicated (m -> m&7), K-permuted ----
    FragU a3[2];
#pragma unroll
    for (int ks = 0; ks < 2; ++ks) {
        float f[8];
#pragma unroll
        for (int jj = 0; jj < 8; ++jj) f[jj] = W3[(c & 7) * 64 + physj(ks, q, jj)];
#pragma unroll
        for (int p = 0; p < 4; ++p) a3[ks].u[p] = pk16(f[2 * p], f[2 * p + 1]);
    }
    // ---- per-lane constants ----
    v4f vb2[4]; // x TSCALE (C-init for scaled z2)
#pragma unroll
    for (int mt = 0; mt < 4; ++mt) {
        const int j0 = 16 * mt + 4 * q;
        vb2[mt][0] = TSCALE * b2[j0]; vb2[mt][1] = TSCALE * b2[j0 + 1];
        vb2[mt][2] = TSCALE * b2[j0 + 2]; vb2[mt][3] = TSCALE * b2[j0 + 3];
    }
    v4f vb3;
#pragma unroll
    for (int r = 0; r < 4; ++r) vb3[r] = b3[(4 * q + r) & 7];

    // ---- x state: ALL lanes hold xr[r] = x[myrow][(4q+r)&7] (duplicated) ----
    float xr[4];
    {
        float4 v = *(const float4*)(x0 + (size_t)myrow * 8 + 4 * (q & 1));
        xr[0] = v.x; xr[1] = v.y; xr[2] = v.z; xr[3] = v.w;
    }
    const v4f vzero = {0.f, 0.f, 0.f, 0.f};
    v2f gv = {0.f, 0.f};

    // ================= iteration 0: pure forward at (x0, t=0) =================
    {
        FragU bx;
        bx.u[0] = pk16(xr[0], xr[1]);
        bx.u[1] = pk16(xr[2], xr[3]);
        bx.u[2] = pk16(0.0f, 1.0f);
        bx.u[3] = 0u;
        v4f d1[4];
#pragma unroll
        for (int mt = 0; mt < 4; ++mt)
            d1[mt] = __builtin_amdgcn_mfma_f32_16x16x32_f16(a1[mt].h, bx.h, vzero, 0, 0, 0);
        uint2 ph[4];
#pragma unroll
        for (int mt = 0; mt < 4; ++mt) {
            ph[mt].x = pk16(ftanh_s(d1[mt][0]), ftanh_s(d1[mt][1]));
            ph[mt].y = pk16(ftanh_s(d1[mt][2]), ftanh_s(d1[mt][3]));
        }
        FragU bh[2];
        rename(ph, bh);
        v4f d2[4];
#pragma unroll
        for (int mt = 0; mt < 4; ++mt) {
            d2[mt] = __builtin_amdgcn_mfma_f32_16x16x32_f16(a2[mt][0].h, bh[0].h, vb2[mt], 0, 0, 0);
            d2[mt] = __builtin_amdgcn_mfma_f32_16x16x32_f16(a2[mt][1].h, bh[1].h, d2[mt], 0, 0, 0);
        }
#pragma unroll
        for (int mt = 0; mt < 4; ++mt) {
            ph[mt].x = pk16(ftanh_s(d2[mt][0]), ftanh_s(d2[mt][1]));
            ph[mt].y = pk16(ftanh_s(d2[mt][2]), ftanh_s(d2[mt][3]));
        }
        FragU bh2[2];
        rename(ph, bh2);
        v4f d3;
        d3 = __builtin_amdgcn_mfma_f32_16x16x32_f16(a3[0].h, bh2[0].h, vb3, 0, 0, 0);
        d3 = __builtin_amdgcn_mfma_f32_16x16x32_f16(a3[1].h, bh2[1].h, d3, 0, 0, 0);
#pragma unroll
        for (int r = 0; r < 4; ++r) xr[r] = fmaf(dt, d3[r], xr[r]);
    }

    // ====== iterations i = 1..n-1: bwd(i-1) + fwd(i) from one L1 eval ======
    float tp = 0.0f; // t_{i-1}
    for (int i = 1; i < n; ++i) {
        FragU bx; // [x_i; t_{i-1}; 1]
        bx.u[0] = pk16(xr[0], xr[1]);
        bx.u[1] = pk16(xr[2], xr[3]);
        bx.u[2] = pk16(tp, 1.0f);
        bx.u[3] = 0u;
        tp += dt;
        v4f d1[4];
#pragma unroll
        for (int mt = 0; mt < 4; ++mt)
            d1[mt] = __builtin_amdgcn_mfma_f32_16x16x32_f16(a1[mt].h, bx.h, vzero, 0, 0, 0);

        // th1b = tanh(z1 @ t_{i-1}); om1 = 1 - th1b^2 (packed math)
        uint2 phb[4], pom[4];
#pragma unroll
        for (int mt = 0; mt < 4; ++mt) {
            v2f th01 = {ftanh_s(d1[mt][0]), ftanh_s(d1[mt][1])};
            v2f th23 = {ftanh_s(d1[mt][2]), ftanh_s(d1[mt][3])};
            v2f om01 = v2f{1.f, 1.f} - th01 * th01;
            v2f om23 = v2f{1.f, 1.f} - th23 * th23;
            phb[mt].x = pk16v(th01);
            phb[mt].y = pk16v(th23);
            pom[mt].x = pk16v(om01);
            pom[mt].y = pk16v(om23);
        }
        FragU bhb[2], bo[2];
        rename(phb, bhb);
        rename(pom, bo);

        v4f z2b[4], sg[4], dz2[4];
#pragma unroll
        for (int mt = 0; mt < 4; ++mt) {
            z2b[mt] = __builtin_amdgcn_mfma_f32_16x16x32_f16(a2[mt][0].h, bhb[0].h, vb2[mt], 0, 0, 0);
            z2b[mt] = __builtin_amdgcn_mfma_f32_16x16x32_f16(a2[mt][1].h, bhb[1].h, z2b[mt], 0, 0, 0);
            sg[mt] = __builtin_amdgcn_mfma_f32_16x16x32_f16(a2g[mt][0].h, bo[0].h, vzero, 0, 0, 0);
            sg[mt] = __builtin_amdgcn_mfma_f32_16x16x32_f16(a2g[mt][1].h, bo[1].h, sg[mt], 0, 0, 0);
            dz2[mt] = __builtin_amdgcn_mfma_f32_16x16x32_f16(a2d[mt][0].h, bo[0].h, vzero, 0, 0, 0);
            dz2[mt] = __builtin_amdgcn_mfma_f32_16x16x32_f16(a2d[mt][1].h, bo[1].h, dz2[mt], 0, 0, 0);
        }

        // th2b = tanh(z2b). g += om2*sg (w3c pre-folded). th2f = th2b+om2*dz2.
        uint2 ph2[4];
#pragma unroll
        for (int mt = 0; mt < 4; ++mt) {
            v2f th01 = {ftanh_s(z2b[mt][0]), ftanh_s(z2b[mt][1])};
            v2f th23 = {ftanh_s(z2b[mt][2]), ftanh_s(z2b[mt][3])};
            v2f om01 = v2f{1.f, 1.f} - th01 * th01;
            v2f om23 = v2f{1.f, 1.f} - th23 * th23;
            gv += om01 * v2f{sg[mt][0], sg[mt][1]};
            gv += om23 * v2f{sg[mt][2], sg[mt][3]};
            v2f tf01 = om01 * v2f{dz2[mt][0], dz2[mt][1]} + th01;
            v2f tf23 = om23 * v2f{dz2[mt][2], dz2[mt][3]} + th23;
            ph2[mt].x = pk16v(tf01);
            ph2[mt].y = pk16v(tf23);
        }
        FragU bh2[2];
        rename(ph2, bh2);
        v4f d3;
        d3 = __builtin_amdgcn_mfma_f32_16x16x32_f16(a3[0].h, bh2[0].h, vb3, 0, 0, 0);
        d3 = __builtin_amdgcn_mfma_f32_16x16x32_f16(a3[1].h, bh2[1].h, d3, 0, 0, 0);
#pragma unroll
        for (int r = 0; r < 4; ++r) xr[r] = fmaf(dt, d3[r], xr[r]);
    }

    // ============ final bwd at (x_n, t_{n-1}) ============
    {
        FragU bx;
        bx.u[0] = pk16(xr[0], xr[1]);
        bx.u[1] = pk16(xr[2], xr[3]);
        bx.u[2] = pk16(tp, 1.0f); // tp == (n-1)*dt
        bx.u[3] = 0u;
        v4f d1[4];
#pragma unroll
        for (int mt = 0; mt < 4; ++mt)
            d1[mt] = __builtin_amdgcn_mfma_f32_16x16x32_f16(a1[mt].h, bx.h, vzero, 0, 0, 0);
        uint2 phb[4], pom[4];
#pragma unroll
        for (int mt = 0; mt < 4; ++mt) {
            v2f th01 = {ftanh_s(d1[mt][0]), ftanh_s(d1[mt][1])};
            v2f th23 = {ftanh_s(d1[mt][2]), ftanh_s(d1[mt][3])};
            v2f om01 = v2f{1.f, 1.f} - th01 * th01;
            v2f om23 = v2f{1.f, 1.f} - th23 * th23;
            phb[mt].x = pk16v(th01);
            phb[mt].y = pk16v(th23);
            pom[mt].x = pk16v(om01);
            pom[mt].y = pk16v(om23);
        }
        FragU bhb[2], bo[2];
        rename(phb, bhb);
        rename(pom, bo);
        v4f z2b[4], sg[4];
#pragma unroll
        for (int mt = 0; mt < 4; ++mt) {
            z2b[mt] = __builtin_amdgcn_mfma_f32_16x16x32_f16(a2[mt][0].h, bhb[0].h, vb2[mt], 0, 0, 0);
            z2b[mt] = __builtin_amdgcn_mfma_f32_16x16x32_f16(a2[mt][1].h, bhb[1].h, z2b[mt], 0, 0, 0);
            sg[mt] = __builtin_amdgcn_mfma_f32_16x16x32_f16(a2g[mt][0].h, bo[0].h, vzero, 0, 0, 0);
            sg[mt] = __builtin_amdgcn_mfma_f32_16x16x32_f16(a2g[mt][1].h, bo[1].h, sg[mt], 0, 0, 0);
        }
#pragma unroll
        for (int mt = 0; mt < 4; ++mt) {
            v2f th01 = {ftanh_s(z2b[mt][0]), ftanh_s(z2b[mt][1])};
            v2f th23 = {ftanh_s(z2b[mt][2]), ftanh_s(z2b[mt][3])};
            v2f om01 = v2f{1.f, 1.f} - th01 * th01;
            v2f om23 = v2f{1.f, 1.f} - th23 * th23;
            gv += om01 * v2f{sg[mt][0], sg[mt][1]};
            gv += om23 * v2f{sg[mt][2], sg[mt][3]};
        }
    }

    // ---- epilogue ----
    float g = gv.x + gv.y;
    g += __shfl_xor(g, 16);
    g += __shfl_xor(g, 32);
    // lanes c>=8 duplicate lanes c-8 (same row) — only c<8 stores.
    if (q < 2 && c < 8) {
        float4 st = {xr[0], xr[1], xr[2], xr[3]};
        *(float4*)(out + (size_t)(row0 + c) * 8 + 4 * q) = st;
    }
    if (q == 0 && c < 8) out[(size_t)rows * 8 + row0 + c] = dt * g;
}

extern "C" void kernel_launch(void* const* d_in, const int* in_sizes, int n_in,
                              void* d_out, int out_size, void* d_ws, size_t ws_size,
                              hipStream_t stream) {
    const float* x0 = (const float*)d_in[0];
    const float* W1 = (const float*)d_in[1];
    const float* b1 = (const float*)d_in[2];
    const float* W2 = (const float*)d_in[3];
    const float* b2 = (const float*)d_in[4];
    const float* W3 = (const float*)d_in[5];
    const float* b3 = (const float*)d_in[6];
    const int* ns = (const int*)d_in[7];
    float* out = (float*)d_out;
    const int rows = in_sizes[0] / 8; // 32768

    hipLaunchKernelGGL(cnf_fused, dim3(rows / 32), dim3(256), 0, stream,
                       x0, W1, b1, W2, b2, W3, b3, ns, out, rows);
}

// Round 2
// 326.443 us; speedup vs baseline: 3.2629x; 3.2629x over previous
//
#include <hip/hip_runtime.h>

// ContinuousNormalizingFlow: B=32768 rows, D=8, H=64, 100 Euler steps.
// R18: R17's occupancy-doubling (8 rows/wave duplicated into both halves
// of the 16-wide B tile -> 4096 waves) but WITHOUT the launch_bounds(256,4)
// floor. R17 post-mortem: the (256,4) bound forced a 64-VGPR budget, the
// ~124-reg live state spilled to scratch (FETCH_SIZE 676KB -> 3.49GB,
// HBM 45% of peak, 1030us). Occupancy DID double as predicted (17->45%),
// so the theory stands; only the register cap was wrong. With (256,2) the
// allocator lands at ~124 VGPRs naturally (R16 measured), and 124 <= 128
// already admits 4 waves/SIMD in hardware (waves step at VGPR 64/128/256).

#define TSCALE 2.885390081777926815f // 2*log2(e)

// tanh from PRE-SCALED z (z = 2*log2e*x): 1 - 2/(2^z + 1). inf-safe.
__device__ __forceinline__ float ftanh_s(float z) {
    float e = __builtin_amdgcn_exp2f(z);
    float r = __builtin_amdgcn_rcpf(e + 1.0f);
    return fmaf(-2.0f, r, 1.0f);
}

typedef __attribute__((ext_vector_type(8))) _Float16 v8h; // 8 f16 (4 VGPRs)
typedef __attribute__((ext_vector_type(2))) __fp16 v2fp; // cvt_pkrtz result
typedef __attribute__((ext_vector_type(4))) float v4f;   // MFMA C/D
typedef __attribute__((ext_vector_type(2))) float v2f;   // packed fp32 pair

union FragU {
    v8h h;
    unsigned u[4];
};

// f16 pair pack: single v_cvt_pkrtz_f16_f32. a -> low half.
__device__ __forceinline__ unsigned pk16(float a, float b) {
    v2fp t = __builtin_amdgcn_cvt_pkrtz(a, b);
    return __builtin_bit_cast(unsigned, t);
}
__device__ __forceinline__ unsigned pk16v(v2f v) { return pk16(v.x, v.y); }

// K-permutation for W2/W3 frags: slot (ks,q,jj) <- physical j.
__device__ __forceinline__ int physj(int ks, int q, int jj) {
    return 16 * (ks + 2 * (jj >> 2)) + 4 * q + (jj & 3);
}

// Rename C-fragment packs (ph[4]: per-mt {r01,r23}) into the B-frag pair.
__device__ __forceinline__ void rename(const uint2 ph[4], FragU bh[2]) {
#pragma unroll
    for (int ks = 0; ks < 2; ++ks) {
        bh[ks].u[0] = ph[ks].x;
        bh[ks].u[1] = ph[ks].y;
        bh[ks].u[2] = ph[ks + 2].x;
        bh[ks].u[3] = ph[ks + 2].y;
    }
}

__global__ __launch_bounds__(256, 2) void cnf_fused(
    const float* __restrict__ x0, const float* __restrict__ W1,
    const float* __restrict__ b1, const float* __restrict__ W2,
    const float* __restrict__ b2, const float* __restrict__ W3,
    const float* __restrict__ b3, const int* __restrict__ nsp,
    float* __restrict__ out, int rows) {
    const int tid = threadIdx.x;
    const int w = tid >> 6;
    const int lane = tid & 63;
    const int c = lane & 15;
    const int q = lane >> 4;
    // 8 rows per wave; lanes c and c+8 duplicate the same row so all 16
    // B-tile columns stay finite (inf/nan-free) at zero extra VALU cost.
    const int row0 = blockIdx.x * 32 + w * 8;
    const int myrow = row0 + (c & 7);

    const int n = *nsp;
    const float dt = 1.0f / (float)n;

    // ---- A1 (x TSCALE): [x;t;1] layout. q0 jj0-3 = W1[:,0:4], q0 jj4 =
    // W1[:,8] (t), q0 jj5 = b1, q1 jj0-3 = W1[:,4:8], all else 0. ----
    FragU a1[4];
#pragma unroll
    for (int mt = 0; mt < 4; ++mt) {
        const int m = 16 * mt + c;
        float f[8] = {0.f, 0.f, 0.f, 0.f, 0.f, 0.f, 0.f, 0.f};
        if (q == 0) {
#pragma unroll
            for (int jj = 0; jj < 4; ++jj) f[jj] = TSCALE * W1[m * 9 + jj];
            f[4] = TSCALE * W1[m * 9 + 8];
            f[5] = TSCALE * b1[m];
        } else if (q == 1) {
#pragma unroll
            for (int jj = 0; jj < 4; ++jj) f[jj] = TSCALE * W1[m * 9 + 4 + jj];
        }
#pragma unroll
        for (int p = 0; p < 4; ++p) a1[mt].u[p] = pk16(f[2 * p], f[2 * p + 1]);
    }
    // ---- A2 (x TSCALE) K-perm; a2g = w3c[m]*W2*w1r[h]; a2d = W2*(dt*w1t[h]).
    // w1r[h] = sum_k W1[h][0:8]; w3c[m] = sum_d W3[d][m] — computed inline
    // (L2-broadcast loads; prep kernel eliminated). ----
    FragU a2[4][2], a2g[4][2], a2d[4][2];
#pragma unroll
    for (int mt = 0; mt < 4; ++mt) {
        const int m = 16 * mt + c;
        float w3cm = 0.f;
#pragma unroll
        for (int d = 0; d < 8; ++d) w3cm += W3[d * 64 + m];
#pragma unroll
        for (int ks = 0; ks < 2; ++ks) {
            float f[8], fg[8], fd[8];
#pragma unroll
            for (int jj = 0; jj < 8; ++jj) {
                const int pj = physj(ks, q, jj);
                const float wv = W2[m * 64 + pj];
                float w1r = 0.f;
#pragma unroll
                for (int k = 0; k < 8; ++k) w1r += W1[pj * 9 + k];
                f[jj] = TSCALE * wv;
                fg[jj] = w3cm * wv * w1r;
                fd[jj] = wv * (dt * W1[pj * 9 + 8]);
            }
#pragma unroll
            for (int p = 0; p < 4; ++p) {
                a2[mt][ks].u[p] = pk16(f[2 * p], f[2 * p + 1]);
                a2g[mt][ks].u[p] = pk16(fg[2 * p], fg[2 * p + 1]);
                a2d[mt][ks].u[p] = pk16(fd[2 * p], fd[2 * p + 1]);
            }
        }
    }
    // ---- A3: W3 rows duplicated (m -> m&7), K-permuted ----
    FragU a3[2];
#pragma unroll
    for (int ks = 0; ks < 2; ++ks) {
        float f[8];
#pragma unroll
        for (int jj = 0; jj < 8; ++jj) f[jj] = W3[(c & 7) * 64 + physj(ks, q, jj)];
#pragma unroll
        for (int p = 0; p < 4; ++p) a3[ks].u[p] = pk16(f[2 * p], f[2 * p + 1]);
    }
    // ---- per-lane constants ----
    v4f vb2[4]; // x TSCALE (C-init for scaled z2)
#pragma unroll
    for (int mt = 0; mt < 4; ++mt) {
        const int j0 = 16 * mt + 4 * q;
        vb2[mt][0] = TSCALE * b2[j0]; vb2[mt][1] = TSCALE * b2[j0 + 1];
        vb2[mt][2] = TSCALE * b2[j0 + 2]; vb2[mt][3] = TSCALE * b2[j0 + 3];
    }
    v4f vb3;
#pragma unroll
    for (int r = 0; r < 4; ++r) vb3[r] = b3[(4 * q + r) & 7];

    // ---- x state: ALL lanes hold xr[r] = x[myrow][(4q+r)&7] (duplicated) ----
    float xr[4];
    {
        float4 v = *(const float4*)(x0 + (size_t)myrow * 8 + 4 * (q & 1));
        xr[0] = v.x; xr[1] = v.y; xr[2] = v.z; xr[3] = v.w;
    }
    const v4f vzero = {0.f, 0.f, 0.f, 0.f};
    v2f gv = {0.f, 0.f};

    // ================= iteration 0: pure forward at (x0, t=0) =================
    {
        FragU bx;
        bx.u[0] = pk16(xr[0], xr[1]);
        bx.u[1] = pk16(xr[2], xr[3]);
        bx.u[2] = pk16(0.0f, 1.0f);
        bx.u[3] = 0u;
        v4f d1[4];
#pragma unroll
        for (int mt = 0; mt < 4; ++mt)
            d1[mt] = __builtin_amdgcn_mfma_f32_16x16x32_f16(a1[mt].h, bx.h, vzero, 0, 0, 0);
        uint2 ph[4];
#pragma unroll
        for (int mt = 0; mt < 4; ++mt) {
            ph[mt].x = pk16(ftanh_s(d1[mt][0]), ftanh_s(d1[mt][1]));
            ph[mt].y = pk16(ftanh_s(d1[mt][2]), ftanh_s(d1[mt][3]));
        }
        FragU bh[2];
        rename(ph, bh);
        v4f d2[4];
#pragma unroll
        for (int mt = 0; mt < 4; ++mt) {
            d2[mt] = __builtin_amdgcn_mfma_f32_16x16x32_f16(a2[mt][0].h, bh[0].h, vb2[mt], 0, 0, 0);
            d2[mt] = __builtin_amdgcn_mfma_f32_16x16x32_f16(a2[mt][1].h, bh[1].h, d2[mt], 0, 0, 0);
        }
#pragma unroll
        for (int mt = 0; mt < 4; ++mt) {
            ph[mt].x = pk16(ftanh_s(d2[mt][0]), ftanh_s(d2[mt][1]));
            ph[mt].y = pk16(ftanh_s(d2[mt][2]), ftanh_s(d2[mt][3]));
        }
        FragU bh2[2];
        rename(ph, bh2);
        v4f d3;
        d3 = __builtin_amdgcn_mfma_f32_16x16x32_f16(a3[0].h, bh2[0].h, vb3, 0, 0, 0);
        d3 = __builtin_amdgcn_mfma_f32_16x16x32_f16(a3[1].h, bh2[1].h, d3, 0, 0, 0);
#pragma unroll
        for (int r = 0; r < 4; ++r) xr[r] = fmaf(dt, d3[r], xr[r]);
    }

    // ====== iterations i = 1..n-1: bwd(i-1) + fwd(i) from one L1 eval ======
    float tp = 0.0f; // t_{i-1}
    for (int i = 1; i < n; ++i) {
        FragU bx; // [x_i; t_{i-1}; 1]
        bx.u[0] = pk16(xr[0], xr[1]);
        bx.u[1] = pk16(xr[2], xr[3]);
        bx.u[2] = pk16(tp, 1.0f);
        bx.u[3] = 0u;
        tp += dt;
        v4f d1[4];
#pragma unroll
        for (int mt = 0; mt < 4; ++mt)
            d1[mt] = __builtin_amdgcn_mfma_f32_16x16x32_f16(a1[mt].h, bx.h, vzero, 0, 0, 0);

        // th1b = tanh(z1 @ t_{i-1}); om1 = 1 - th1b^2 (packed math)
        uint2 phb[4], pom[4];
#pragma unroll
        for (int mt = 0; mt < 4; ++mt) {
            v2f th01 = {ftanh_s(d1[mt][0]), ftanh_s(d1[mt][1])};
            v2f th23 = {ftanh_s(d1[mt][2]), ftanh_s(d1[mt][3])};
            v2f om01 = v2f{1.f, 1.f} - th01 * th01;
            v2f om23 = v2f{1.f, 1.f} - th23 * th23;
            phb[mt].x = pk16v(th01);
            phb[mt].y = pk16v(th23);
            pom[mt].x = pk16v(om01);
            pom[mt].y = pk16v(om23);
        }
        FragU bhb[2], bo[2];
        rename(phb, bhb);
        rename(pom, bo);

        v4f z2b[4], sg[4], dz2[4];
#pragma unroll
        for (int mt = 0; mt < 4; ++mt) {
            z2b[mt] = __builtin_amdgcn_mfma_f32_16x16x32_f16(a2[mt][0].h, bhb[0].h, vb2[mt], 0, 0, 0);
            z2b[mt] = __builtin_amdgcn_mfma_f32_16x16x32_f16(a2[mt][1].h, bhb[1].h, z2b[mt], 0, 0, 0);
            sg[mt] = __builtin_amdgcn_mfma_f32_16x16x32_f16(a2g[mt][0].h, bo[0].h, vzero, 0, 0, 0);
            sg[mt] = __builtin_amdgcn_mfma_f32_16x16x32_f16(a2g[mt][1].h, bo[1].h, sg[mt], 0, 0, 0);
            dz2[mt] = __builtin_amdgcn_mfma_f32_16x16x32_f16(a2d[mt][0].h, bo[0].h, vzero, 0, 0, 0);
            dz2[mt] = __builtin_amdgcn_mfma_f32_16x16x32_f16(a2d[mt][1].h, bo[1].h, dz2[mt], 0, 0, 0);
        }

        // th2b = tanh(z2b). g += om2*sg (w3c pre-folded). th2f = th2b+om2*dz2.
        uint2 ph2[4];
#pragma unroll
        for (int mt = 0; mt < 4; ++mt) {
            v2f th01 = {ftanh_s(z2b[mt][0]), ftanh_s(z2b[mt][1])};
            v2f th23 = {ftanh_s(z2b[mt][2]), ftanh_s(z2b[mt][3])};
            v2f om01 = v2f{1.f, 1.f} - th01 * th01;
            v2f om23 = v2f{1.f, 1.f} - th23 * th23;
            gv += om01 * v2f{sg[mt][0], sg[mt][1]};
            gv += om23 * v2f{sg[mt][2], sg[mt][3]};
            v2f tf01 = om01 * v2f{dz2[mt][0], dz2[mt][1]} + th01;
            v2f tf23 = om23 * v2f{dz2[mt][2], dz2[mt][3]} + th23;
            ph2[mt].x = pk16v(tf01);
            ph2[mt].y = pk16v(tf23);
        }
        FragU bh2[2];
        rename(ph2, bh2);
        v4f d3;
        d3 = __builtin_amdgcn_mfma_f32_16x16x32_f16(a3[0].h, bh2[0].h, vb3, 0, 0, 0);
        d3 = __builtin_amdgcn_mfma_f32_16x16x32_f16(a3[1].h, bh2[1].h, d3, 0, 0, 0);
#pragma unroll
        for (int r = 0; r < 4; ++r) xr[r] = fmaf(dt, d3[r], xr[r]);
    }

    // ============ final bwd at (x_n, t_{n-1}) ============
    {
        FragU bx;
        bx.u[0] = pk16(xr[0], xr[1]);
        bx.u[1] = pk16(xr[2], xr[3]);
        bx.u[2] = pk16(tp, 1.0f); // tp == (n-1)*dt
        bx.u[3] = 0u;
        v4f d1[4];
#pragma unroll
        for (int mt = 0; mt < 4; ++mt)
            d1[mt] = __builtin_amdgcn_mfma_f32_16x16x32_f16(a1[mt].h, bx.h, vzero, 0, 0, 0);
        uint2 phb[4], pom[4];
#pragma unroll
        for (int mt = 0; mt < 4; ++mt) {
            v2f th01 = {ftanh_s(d1[mt][0]), ftanh_s(d1[mt][1])};
            v2f th23 = {ftanh_s(d1[mt][2]), ftanh_s(d1[mt][3])};
            v2f om01 = v2f{1.f, 1.f} - th01 * th01;
            v2f om23 = v2f{1.f, 1.f} - th23 * th23;
            phb[mt].x = pk16v(th01);
            phb[mt].y = pk16v(th23);
            pom[mt].x = pk16v(om01);
            pom[mt].y = pk16v(om23);
        }
        FragU bhb[2], bo[2];
        rename(phb, bhb);
        rename(pom, bo);
        v4f z2b[4], sg[4];
#pragma unroll
        for (int mt = 0; mt < 4; ++mt) {
            z2b[mt] = __builtin_amdgcn_mfma_f32_16x16x32_f16(a2[mt][0].h, bhb[0].h, vb2[mt], 0, 0, 0);
            z2b[mt] = __builtin_amdgcn_mfma_f32_16x16x32_f16(a2[mt][1].h, bhb[1].h, z2b[mt], 0, 0, 0);
            sg[mt] = __builtin_amdgcn_mfma_f32_16x16x32_f16(a2g[mt][0].h, bo[0].h, vzero, 0, 0, 0);
            sg[mt] = __builtin_amdgcn_mfma_f32_16x16x32_f16(a2g[mt][1].h, bo[1].h, sg[mt], 0, 0, 0);
        }
#pragma unroll
        for (int mt = 0; mt < 4; ++mt) {
            v2f th01 = {ftanh_s(z2b[mt][0]), ftanh_s(z2b[mt][1])};
            v2f th23 = {ftanh_s(z2b[mt][2]), ftanh_s(z2b[mt][3])};
            v2f om01 = v2f{1.f, 1.f} - th01 * th01;
            v2f om23 = v2f{1.f, 1.f} - th23 * th23;
            gv += om01 * v2f{sg[mt][0], sg[mt][1]};
            gv += om23 * v2f{sg[mt][2], sg[mt][3]};
        }
    }

    // ---- epilogue ----
    float g = gv.x + gv.y;
    g += __shfl_xor(g, 16);
    g += __shfl_xor(g, 32);
    // lanes c>=8 duplicate lanes c-8 (same row) — only c<8 stores.
    if (q < 2 && c < 8) {
        float4 st = {xr[0], xr[1], xr[2], xr[3]};
        *(float4*)(out + (size_t)(row0 + c) * 8 + 4 * q) = st;
    }
    if (q == 0 && c < 8) out[(size_t)rows * 8 + row0 + c] = dt * g;
}

extern "C" void kernel_launch(void* const* d_in, const int* in_sizes, int n_in,
                              void* d_out, int out_size, void* d_ws, size_t ws_size,
                              hipStream_t stream) {
    const float* x0 = (const float*)d_in[0];
    const float* W1 = (const float*)d_in[1];
    const float* b1 = (const float*)d_in[2];
    const float* W2 = (const float*)d_in[3];
    const float* b2 = (const float*)d_in[4];
    const float* W3 = (const float*)d_in[5];
    const float* b3 = (const float*)d_in[6];
    const int* ns = (const int*)d_in[7];
    float* out = (float*)d_out;
    const int rows = in_sizes[0] / 8; // 32768

    hipLaunchKernelGGL(cnf_fused, dim3(rows / 32), dim3(256), 0, stream,
                       x0, W1, b1, W2, b2, W3, b3, ns, out, rows);
}

// Round 3
// 206.617 us; speedup vs baseline: 5.1552x; 1.5799x over previous
//
#include <hip/hip_runtime.h>

// ContinuousNormalizingFlow: B=32768 rows, D=8, H=64, 100 Euler steps.
// R19: R16 geometry (16 rows/wave, 2048 waves) + register diet to cross
// the 3-waves/SIMD boundary. R18 post-mortem: rocprof VGPR_Count=124 is
// ARCH regs only; ~64 AGPRs (16 live v4f accumulators) ride on top in
// gfx950's unified file -> total ~188 -> 2 waves/SIMD, and time scales
// linearly with issued work (R18 = 2x work = 1.93x time) => issue-bound.
// Diet: drop a2g/a2d A-fragments (64 regs). dz2 = a2 x (om1 (x) c) with
// c[j]=dt*w1t[j]/TSCALE packed f16 (8 regs, one v_pk_mul_f16 per pair);
// sg = a2 x (om1 (x) w1r) with w1r packed f16 (8 regs); row scale
// w3c[m]/TSCALE moves to the gv update as 16 f32 regs. TSCALE cancels
// exactly; f16 rounding magnitudes match the old a2d/a2g quantization.
// Net ~-32 regs -> ~156 total -> 3 waves/SIMD; +24 VALU insts/iter (+3%).

#define TSCALE 2.885390081777926815f // 2*log2(e)

// tanh from PRE-SCALED z (z = 2*log2e*x): 1 - 2/(2^z + 1). inf-safe.
__device__ __forceinline__ float ftanh_s(float z) {
    float e = __builtin_amdgcn_exp2f(z);
    float r = __builtin_amdgcn_rcpf(e + 1.0f);
    return fmaf(-2.0f, r, 1.0f);
}

typedef __attribute__((ext_vector_type(8))) _Float16 v8h; // 8 f16 (4 VGPRs)
typedef __attribute__((ext_vector_type(2))) __fp16 v2fp; // cvt_pkrtz result
typedef __attribute__((ext_vector_type(4))) float v4f;   // MFMA C/D
typedef __attribute__((ext_vector_type(2))) float v2f;   // packed fp32 pair

union FragU {
    v8h h;
    unsigned u[4];
};

// f16 pair pack: single v_cvt_pkrtz_f16_f32. a -> low half.
__device__ __forceinline__ unsigned pk16(float a, float b) {
    v2fp t = __builtin_amdgcn_cvt_pkrtz(a, b);
    return __builtin_bit_cast(unsigned, t);
}
__device__ __forceinline__ unsigned pk16v(v2f v) { return pk16(v.x, v.y); }

// packed f16 elementwise multiply: one v_pk_mul_f16.
__device__ __forceinline__ unsigned pmul16(unsigned a, unsigned b) {
    v2fp x = __builtin_bit_cast(v2fp, a);
    v2fp y = __builtin_bit_cast(v2fp, b);
    v2fp r = x * y;
    return __builtin_bit_cast(unsigned, r);
}

// K-permutation for W2/W3 frags: slot (ks,q,jj) <- physical j.
__device__ __forceinline__ int physj(int ks, int q, int jj) {
    return 16 * (ks + 2 * (jj >> 2)) + 4 * q + (jj & 3);
}

// Rename C-fragment packs (ph[4]: per-mt {r01,r23}) into the B-frag pair.
__device__ __forceinline__ void rename(const uint2 ph[4], FragU bh[2]) {
#pragma unroll
    for (int ks = 0; ks < 2; ++ks) {
        bh[ks].u[0] = ph[ks].x;
        bh[ks].u[1] = ph[ks].y;
        bh[ks].u[2] = ph[ks + 2].x;
        bh[ks].u[3] = ph[ks + 2].y;
    }
}

__global__ __launch_bounds__(256, 2) void cnf_fused(
    const float* __restrict__ x0, const float* __restrict__ W1,
    const float* __restrict__ b1, const float* __restrict__ W2,
    const float* __restrict__ b2, const float* __restrict__ W3,
    const float* __restrict__ b3, const int* __restrict__ nsp,
    float* __restrict__ out, int rows) {
    const int tid = threadIdx.x;
    const int w = tid >> 6;
    const int lane = tid & 63;
    const int c = lane & 15;
    const int q = lane >> 4;
    const int row0 = blockIdx.x * 64 + w * 16;

    const int n = *nsp;
    const float dt = 1.0f / (float)n;
    const float inv_ts = 1.0f / TSCALE;

    // ---- A1 (x TSCALE): [x;t;1] layout. q0 jj0-3 = W1[:,0:4], q0 jj4 =
    // W1[:,8] (t), q0 jj5 = b1, q1 jj0-3 = W1[:,4:8], all else 0. ----
    FragU a1[4];
#pragma unroll
    for (int mt = 0; mt < 4; ++mt) {
        const int m = 16 * mt + c;
        float f[8] = {0.f, 0.f, 0.f, 0.f, 0.f, 0.f, 0.f, 0.f};
        if (q == 0) {
#pragma unroll
            for (int jj = 0; jj < 4; ++jj) f[jj] = TSCALE * W1[m * 9 + jj];
            f[4] = TSCALE * W1[m * 9 + 8];
            f[5] = TSCALE * b1[m];
        } else if (q == 1) {
#pragma unroll
            for (int jj = 0; jj < 4; ++jj) f[jj] = TSCALE * W1[m * 9 + 4 + jj];
        }
#pragma unroll
        for (int p = 0; p < 4; ++p) a1[mt].u[p] = pk16(f[2 * p], f[2 * p + 1]);
    }
    // ---- A2 (x TSCALE), K-permuted. (a2g/a2d eliminated: their per-element
    // scalings fold into the B side / gv update below.) ----
    FragU a2[4][2];
#pragma unroll
    for (int mt = 0; mt < 4; ++mt) {
#pragma unroll
        for (int ks = 0; ks < 2; ++ks) {
            float f[8];
#pragma unroll
            for (int jj = 0; jj < 8; ++jj)
                f[jj] = TSCALE * W2[(16 * mt + c) * 64 + physj(ks, q, jj)];
#pragma unroll
            for (int p = 0; p < 4; ++p) a2[mt][ks].u[p] = pk16(f[2 * p], f[2 * p + 1]);
        }
    }
    // ---- fold constants, C-layout j = 16mt+4q+r (pre-rename slot order):
    // cpk = dt*w1t[j]/TSCALE (f16 pairs), w1rpk = sum_k W1[j][0:8] (f16
    // pairs), w3cf = (sum_d W3[d][h])/TSCALE (f32, gv output side). ----
    unsigned cpk[4][2], w1rpk[4][2];
    v4f w3cf[4];
#pragma unroll
    for (int mt = 0; mt < 4; ++mt) {
#pragma unroll
        for (int p = 0; p < 2; ++p) {
            const int j0 = 16 * mt + 4 * q + 2 * p;
            const float c0 = dt * inv_ts * W1[j0 * 9 + 8];
            const float c1 = dt * inv_ts * W1[(j0 + 1) * 9 + 8];
            cpk[mt][p] = pk16(c0, c1);
            float r0 = 0.f, r1 = 0.f;
#pragma unroll
            for (int k = 0; k < 8; ++k) {
                r0 += W1[j0 * 9 + k];
                r1 += W1[(j0 + 1) * 9 + k];
            }
            w1rpk[mt][p] = pk16(r0, r1);
        }
#pragma unroll
        for (int r = 0; r < 4; ++r) {
            const int h = 16 * mt + 4 * q + r;
            float s = 0.f;
#pragma unroll
            for (int d = 0; d < 8; ++d) s += W3[d * 64 + h];
            w3cf[mt][r] = s * inv_ts;
        }
    }
    // ---- A3: W3 rows duplicated (m -> m&7), K-permuted ----
    FragU a3[2];
#pragma unroll
    for (int ks = 0; ks < 2; ++ks) {
        float f[8];
#pragma unroll
        for (int jj = 0; jj < 8; ++jj) f[jj] = W3[(c & 7) * 64 + physj(ks, q, jj)];
#pragma unroll
        for (int p = 0; p < 4; ++p) a3[ks].u[p] = pk16(f[2 * p], f[2 * p + 1]);
    }
    // ---- per-lane constants ----
    v4f vb2[4]; // x TSCALE (C-init for scaled z2)
#pragma unroll
    for (int mt = 0; mt < 4; ++mt) {
        const int j0 = 16 * mt + 4 * q;
        vb2[mt][0] = TSCALE * b2[j0]; vb2[mt][1] = TSCALE * b2[j0 + 1];
        vb2[mt][2] = TSCALE * b2[j0 + 2]; vb2[mt][3] = TSCALE * b2[j0 + 3];
    }
    v4f vb3;
#pragma unroll
    for (int r = 0; r < 4; ++r) vb3[r] = b3[(4 * q + r) & 7];

    // ---- x state: ALL lanes hold xr[r] = x[row0+c][(4q+r)&7] (duplicated) ----
    float xr[4];
    {
        float4 v = *(const float4*)(x0 + (size_t)(row0 + c) * 8 + 4 * (q & 1));
        xr[0] = v.x; xr[1] = v.y; xr[2] = v.z; xr[3] = v.w;
    }
    const v4f vzero = {0.f, 0.f, 0.f, 0.f};
    v2f gv = {0.f, 0.f};

    // ================= iteration 0: pure forward at (x0, t=0) =================
    {
        FragU bx;
        bx.u[0] = pk16(xr[0], xr[1]);
        bx.u[1] = pk16(xr[2], xr[3]);
        bx.u[2] = pk16(0.0f, 1.0f);
        bx.u[3] = 0u;
        v4f d1[4];
#pragma unroll
        for (int mt = 0; mt < 4; ++mt)
            d1[mt] = __builtin_amdgcn_mfma_f32_16x16x32_f16(a1[mt].h, bx.h, vzero, 0, 0, 0);
        uint2 ph[4];
#pragma unroll
        for (int mt = 0; mt < 4; ++mt) {
            ph[mt].x = pk16(ftanh_s(d1[mt][0]), ftanh_s(d1[mt][1]));
            ph[mt].y = pk16(ftanh_s(d1[mt][2]), ftanh_s(d1[mt][3]));
        }
        FragU bh[2];
        rename(ph, bh);
        v4f d2[4];
#pragma unroll
        for (int mt = 0; mt < 4; ++mt) {
            d2[mt] = __builtin_amdgcn_mfma_f32_16x16x32_f16(a2[mt][0].h, bh[0].h, vb2[mt], 0, 0, 0);
            d2[mt] = __builtin_amdgcn_mfma_f32_16x16x32_f16(a2[mt][1].h, bh[1].h, d2[mt], 0, 0, 0);
        }
#pragma unroll
        for (int mt = 0; mt < 4; ++mt) {
            ph[mt].x = pk16(ftanh_s(d2[mt][0]), ftanh_s(d2[mt][1]));
            ph[mt].y = pk16(ftanh_s(d2[mt][2]), ftanh_s(d2[mt][3]));
        }
        FragU bh2[2];
        rename(ph, bh2);
        v4f d3;
        d3 = __builtin_amdgcn_mfma_f32_16x16x32_f16(a3[0].h, bh2[0].h, vb3, 0, 0, 0);
        d3 = __builtin_amdgcn_mfma_f32_16x16x32_f16(a3[1].h, bh2[1].h, d3, 0, 0, 0);
#pragma unroll
        for (int r = 0; r < 4; ++r) xr[r] = fmaf(dt, d3[r], xr[r]);
    }

    // ====== iterations i = 1..n-1: bwd(i-1) + fwd(i) from one L1 eval ======
    float tp = 0.0f; // t_{i-1}
    for (int i = 1; i < n; ++i) {
        FragU bx; // [x_i; t_{i-1}; 1]
        bx.u[0] = pk16(xr[0], xr[1]);
        bx.u[1] = pk16(xr[2], xr[3]);
        bx.u[2] = pk16(tp, 1.0f);
        bx.u[3] = 0u;
        tp += dt;
        v4f d1[4];
#pragma unroll
        for (int mt = 0; mt < 4; ++mt)
            d1[mt] = __builtin_amdgcn_mfma_f32_16x16x32_f16(a1[mt].h, bx.h, vzero, 0, 0, 0);

        // th1b = tanh(z1 @ t_{i-1}); om1 = 1 - th1b^2 (packed math)
        uint2 phb[4], pom[4];
#pragma unroll
        for (int mt = 0; mt < 4; ++mt) {
            v2f th01 = {ftanh_s(d1[mt][0]), ftanh_s(d1[mt][1])};
            v2f th23 = {ftanh_s(d1[mt][2]), ftanh_s(d1[mt][3])};
            v2f om01 = v2f{1.f, 1.f} - th01 * th01;
            v2f om23 = v2f{1.f, 1.f} - th23 * th23;
            phb[mt].x = pk16v(th01);
            phb[mt].y = pk16v(th23);
            pom[mt].x = pk16v(om01);
            pom[mt].y = pk16v(om23);
        }
        // B-side folds: bo2 = om1 (x) c  (dz2), bo3 = om1 (x) w1r  (sg)
        uint2 pb2[4], pb3[4];
#pragma unroll
        for (int mt = 0; mt < 4; ++mt) {
            pb2[mt].x = pmul16(pom[mt].x, cpk[mt][0]);
            pb2[mt].y = pmul16(pom[mt].y, cpk[mt][1]);
            pb3[mt].x = pmul16(pom[mt].x, w1rpk[mt][0]);
            pb3[mt].y = pmul16(pom[mt].y, w1rpk[mt][1]);
        }
        FragU bhb[2], bo2f[2], bo3f[2];
        rename(phb, bhb);
        rename(pb2, bo2f);
        rename(pb3, bo3f);

        v4f z2b[4], sg[4], dz2[4];
#pragma unroll
        for (int mt = 0; mt < 4; ++mt) {
            z2b[mt] = __builtin_amdgcn_mfma_f32_16x16x32_f16(a2[mt][0].h, bhb[0].h, vb2[mt], 0, 0, 0);
            z2b[mt] = __builtin_amdgcn_mfma_f32_16x16x32_f16(a2[mt][1].h, bhb[1].h, z2b[mt], 0, 0, 0);
            sg[mt] = __builtin_amdgcn_mfma_f32_16x16x32_f16(a2[mt][0].h, bo3f[0].h, vzero, 0, 0, 0);
            sg[mt] = __builtin_amdgcn_mfma_f32_16x16x32_f16(a2[mt][1].h, bo3f[1].h, sg[mt], 0, 0, 0);
            dz2[mt] = __builtin_amdgcn_mfma_f32_16x16x32_f16(a2[mt][0].h, bo2f[0].h, vzero, 0, 0, 0);
            dz2[mt] = __builtin_amdgcn_mfma_f32_16x16x32_f16(a2[mt][1].h, bo2f[1].h, dz2[mt], 0, 0, 0);
        }

        // th2b = tanh(z2b). g += om2*(w3cf*sg). th2f = th2b + om2*dz2.
        uint2 ph2[4];
#pragma unroll
        for (int mt = 0; mt < 4; ++mt) {
            v2f th01 = {ftanh_s(z2b[mt][0]), ftanh_s(z2b[mt][1])};
            v2f th23 = {ftanh_s(z2b[mt][2]), ftanh_s(z2b[mt][3])};
            v2f om01 = v2f{1.f, 1.f} - th01 * th01;
            v2f om23 = v2f{1.f, 1.f} - th23 * th23;
            gv += om01 * (v2f{w3cf[mt][0], w3cf[mt][1]} * v2f{sg[mt][0], sg[mt][1]});
            gv += om23 * (v2f{w3cf[mt][2], w3cf[mt][3]} * v2f{sg[mt][2], sg[mt][3]});
            v2f tf01 = om01 * v2f{dz2[mt][0], dz2[mt][1]} + th01;
            v2f tf23 = om23 * v2f{dz2[mt][2], dz2[mt][3]} + th23;
            ph2[mt].x = pk16v(tf01);
            ph2[mt].y = pk16v(tf23);
        }
        FragU bh2[2];
        rename(ph2, bh2);
        v4f d3;
        d3 = __builtin_amdgcn_mfma_f32_16x16x32_f16(a3[0].h, bh2[0].h, vb3, 0, 0, 0);
        d3 = __builtin_amdgcn_mfma_f32_16x16x32_f16(a3[1].h, bh2[1].h, d3, 0, 0, 0);
#pragma unroll
        for (int r = 0; r < 4; ++r) xr[r] = fmaf(dt, d3[r], xr[r]);
    }

    // ============ final bwd at (x_n, t_{n-1}) ============
    {
        FragU bx;
        bx.u[0] = pk16(xr[0], xr[1]);
        bx.u[1] = pk16(xr[2], xr[3]);
        bx.u[2] = pk16(tp, 1.0f); // tp == (n-1)*dt
        bx.u[3] = 0u;
        v4f d1[4];
#pragma unroll
        for (int mt = 0; mt < 4; ++mt)
            d1[mt] = __builtin_amdgcn_mfma_f32_16x16x32_f16(a1[mt].h, bx.h, vzero, 0, 0, 0);
        uint2 phb[4], pom[4];
#pragma unroll
        for (int mt = 0; mt < 4; ++mt) {
            v2f th01 = {ftanh_s(d1[mt][0]), ftanh_s(d1[mt][1])};
            v2f th23 = {ftanh_s(d1[mt][2]), ftanh_s(d1[mt][3])};
            v2f om01 = v2f{1.f, 1.f} - th01 * th01;
            v2f om23 = v2f{1.f, 1.f} - th23 * th23;
            phb[mt].x = pk16v(th01);
            phb[mt].y = pk16v(th23);
            pom[mt].x = pk16v(om01);
            pom[mt].y = pk16v(om23);
        }
        uint2 pb3[4];
#pragma unroll
        for (int mt = 0; mt < 4; ++mt) {
            pb3[mt].x = pmul16(pom[mt].x, w1rpk[mt][0]);
            pb3[mt].y = pmul16(pom[mt].y, w1rpk[mt][1]);
        }
        FragU bhb[2], bo3f[2];
        rename(phb, bhb);
        rename(pb3, bo3f);
        v4f z2b[4], sg[4];
#pragma unroll
        for (int mt = 0; mt < 4; ++mt) {
            z2b[mt] = __builtin_amdgcn_mfma_f32_16x16x32_f16(a2[mt][0].h, bhb[0].h, vb2[mt], 0, 0, 0);
            z2b[mt] = __builtin_amdgcn_mfma_f32_16x16x32_f16(a2[mt][1].h, bhb[1].h, z2b[mt], 0, 0, 0);
            sg[mt] = __builtin_amdgcn_mfma_f32_16x16x32_f16(a2[mt][0].h, bo3f[0].h, vzero, 0, 0, 0);
            sg[mt] = __builtin_amdgcn_mfma_f32_16x16x32_f16(a2[mt][1].h, bo3f[1].h, sg[mt], 0, 0, 0);
        }
#pragma unroll
        for (int mt = 0; mt < 4; ++mt) {
            v2f th01 = {ftanh_s(z2b[mt][0]), ftanh_s(z2b[mt][1])};
            v2f th23 = {ftanh_s(z2b[mt][2]), ftanh_s(z2b[mt][3])};
            v2f om01 = v2f{1.f, 1.f} - th01 * th01;
            v2f om23 = v2f{1.f, 1.f} - th23 * th23;
            gv += om01 * (v2f{w3cf[mt][0], w3cf[mt][1]} * v2f{sg[mt][0], sg[mt][1]});
            gv += om23 * (v2f{w3cf[mt][2], w3cf[mt][3]} * v2f{sg[mt][2], sg[mt][3]});
        }
    }

    // ---- epilogue ----
    float g = gv.x + gv.y;
    g += __shfl_xor(g, 16);
    g += __shfl_xor(g, 32);
    if (q < 2) {
        float4 st = {xr[0], xr[1], xr[2], xr[3]};
        *(float4*)(out + (size_t)(row0 + c) * 8 + 4 * q) = st;
    }
    if (q == 0) out[(size_t)rows * 8 + row0 + c] = dt * g;
}

extern "C" void kernel_launch(void* const* d_in, const int* in_sizes, int n_in,
                              void* d_out, int out_size, void* d_ws, size_t ws_size,
                              hipStream_t stream) {
    const float* x0 = (const float*)d_in[0];
    const float* W1 = (const float*)d_in[1];
    const float* b1 = (const float*)d_in[2];
    const float* W2 = (const float*)d_in[3];
    const float* b2 = (const float*)d_in[4];
    const float* W3 = (const float*)d_in[5];
    const float* b3 = (const float*)d_in[6];
    const int* ns = (const int*)d_in[7];
    float* out = (float*)d_out;
    const int rows = in_sizes[0] / 8; // 32768

    hipLaunchKernelGGL(cnf_fused, dim3(rows / 64), dim3(256), 0, stream,
                       x0, W1, b1, W2, b2, W3, b3, ns, out, rows);
}

// Round 4
// 194.485 us; speedup vs baseline: 5.4768x; 1.0624x over previous
//
#include <hip/hip_runtime.h>

// ContinuousNormalizingFlow: B=32768 rows, D=8, H=64, 100 Euler steps.
// R20: revert to R16 structure (161.4us measured: a2g/a2d pre-folded
// A-fragments, 16 rows/wave, 2048 waves). R18/R19 post-mortems proved:
// (a) occupancy is GRID-capped at 2 waves/SIMD (2048 waves / 1024 SIMDs)
//     -- fewer rows/wave just duplicates VALU work 1:1 (R18: 2x work =
//     1.93x time), so registers are free and a2g/a2d cost nothing;
// (b) the machine is VALU-issue-bound (VALUBusy 63% vs MfmaUtil 27%),
//     so only op-count cuts move the needle.
// Change vs R16: layer-1 om = 1 - th^2 computed directly in PACKED f16
// from the already-packed th (1-2 v_pk_fma_f16 per pair) instead of
// 8 f32 ops + 2 packs per mt. om1 is only ever an f16 MFMA B-operand,
// so this is <=1ulp-f16 numerics change on the logdet path only.
// Saves ~32 VALU ops/iter (~5-8% of VALU busy cycles).

#define TSCALE 2.885390081777926815f // 2*log2(e)

// tanh from PRE-SCALED z (z = 2*log2e*x): 1 - 2/(2^z + 1). inf-safe.
__device__ __forceinline__ float ftanh_s(float z) {
    float e = __builtin_amdgcn_exp2f(z);
    float r = __builtin_amdgcn_rcpf(e + 1.0f);
    return fmaf(-2.0f, r, 1.0f);
}

typedef __attribute__((ext_vector_type(8))) _Float16 v8h; // 8 f16 (4 VGPRs)
typedef __attribute__((ext_vector_type(2))) __fp16 v2fp; // cvt_pkrtz result
typedef __attribute__((ext_vector_type(4))) float v4f;   // MFMA C/D
typedef __attribute__((ext_vector_type(2))) float v2f;   // packed fp32 pair

union FragU {
    v8h h;
    unsigned u[4];
};

// f16 pair pack: single v_cvt_pkrtz_f16_f32. a -> low half.
__device__ __forceinline__ unsigned pk16(float a, float b) {
    v2fp t = __builtin_amdgcn_cvt_pkrtz(a, b);
    return __builtin_bit_cast(unsigned, t);
}
__device__ __forceinline__ unsigned pk16v(v2f v) { return pk16(v.x, v.y); }

// om = 1 - th^2 on a packed f16 pair: v_pk_fma_f16 (contracted) or
// pk_mul+pk_sub. Replaces 8 f32 ops + a pack per uint.
__device__ __forceinline__ unsigned pkom(unsigned thp) {
    v2fp t = __builtin_bit_cast(v2fp, thp);
    v2fp one = {(__fp16)1.0f, (__fp16)1.0f};
    v2fp om = one - t * t;
    return __builtin_bit_cast(unsigned, om);
}

// K-permutation for W2/W3 frags: slot (ks,q,jj) <- physical j.
__device__ __forceinline__ int physj(int ks, int q, int jj) {
    return 16 * (ks + 2 * (jj >> 2)) + 4 * q + (jj & 3);
}

// Rename C-fragment packs (ph[4]: per-mt {r01,r23}) into the B-frag pair.
__device__ __forceinline__ void rename(const uint2 ph[4], FragU bh[2]) {
#pragma unroll
    for (int ks = 0; ks < 2; ++ks) {
        bh[ks].u[0] = ph[ks].x;
        bh[ks].u[1] = ph[ks].y;
        bh[ks].u[2] = ph[ks + 2].x;
        bh[ks].u[3] = ph[ks + 2].y;
    }
}

__global__ __launch_bounds__(256, 2) void cnf_fused(
    const float* __restrict__ x0, const float* __restrict__ W1,
    const float* __restrict__ b1, const float* __restrict__ W2,
    const float* __restrict__ b2, const float* __restrict__ W3,
    const float* __restrict__ b3, const int* __restrict__ nsp,
    float* __restrict__ out, int rows) {
    const int tid = threadIdx.x;
    const int w = tid >> 6;
    const int lane = tid & 63;
    const int c = lane & 15;
    const int q = lane >> 4;
    const int row0 = blockIdx.x * 64 + w * 16;

    const int n = *nsp;
    const float dt = 1.0f / (float)n;

    // ---- A1 (x TSCALE): [x;t;1] layout. q0 jj0-3 = W1[:,0:4], q0 jj4 =
    // W1[:,8] (t), q0 jj5 = b1, q1 jj0-3 = W1[:,4:8], all else 0. ----
    FragU a1[4];
#pragma unroll
    for (int mt = 0; mt < 4; ++mt) {
        const int m = 16 * mt + c;
        float f[8] = {0.f, 0.f, 0.f, 0.f, 0.f, 0.f, 0.f, 0.f};
        if (q == 0) {
#pragma unroll
            for (int jj = 0; jj < 4; ++jj) f[jj] = TSCALE * W1[m * 9 + jj];
            f[4] = TSCALE * W1[m * 9 + 8];
            f[5] = TSCALE * b1[m];
        } else if (q == 1) {
#pragma unroll
            for (int jj = 0; jj < 4; ++jj) f[jj] = TSCALE * W1[m * 9 + 4 + jj];
        }
#pragma unroll
        for (int p = 0; p < 4; ++p) a1[mt].u[p] = pk16(f[2 * p], f[2 * p + 1]);
    }
    // ---- A2 (x TSCALE) K-perm; a2g = w3c[m]*W2*w1r[h]; a2d = W2*(dt*w1t[h]).
    // w1r[h] = sum_k W1[h][0:8]; w3c[m] = sum_d W3[d][m] — computed inline
    // (L2-broadcast loads; prep kernel eliminated). ----
    FragU a2[4][2], a2g[4][2], a2d[4][2];
#pragma unroll
    for (int mt = 0; mt < 4; ++mt) {
        const int m = 16 * mt + c;
        float w3cm = 0.f;
#pragma unroll
        for (int d = 0; d < 8; ++d) w3cm += W3[d * 64 + m];
#pragma unroll
        for (int ks = 0; ks < 2; ++ks) {
            float f[8], fg[8], fd[8];
#pragma unroll
            for (int jj = 0; jj < 8; ++jj) {
                const int pj = physj(ks, q, jj);
                const float wv = W2[m * 64 + pj];
                float w1r = 0.f;
#pragma unroll
                for (int k = 0; k < 8; ++k) w1r += W1[pj * 9 + k];
                f[jj] = TSCALE * wv;
                fg[jj] = w3cm * wv * w1r;
                fd[jj] = wv * (dt * W1[pj * 9 + 8]);
            }
#pragma unroll
            for (int p = 0; p < 4; ++p) {
                a2[mt][ks].u[p] = pk16(f[2 * p], f[2 * p + 1]);
                a2g[mt][ks].u[p] = pk16(fg[2 * p], fg[2 * p + 1]);
                a2d[mt][ks].u[p] = pk16(fd[2 * p], fd[2 * p + 1]);
            }
        }
    }
    // ---- A3: W3 rows duplicated (m -> m&7), K-permuted ----
    FragU a3[2];
#pragma unroll
    for (int ks = 0; ks < 2; ++ks) {
        float f[8];
#pragma unroll
        for (int jj = 0; jj < 8; ++jj) f[jj] = W3[(c & 7) * 64 + physj(ks, q, jj)];
#pragma unroll
        for (int p = 0; p < 4; ++p) a3[ks].u[p] = pk16(f[2 * p], f[2 * p + 1]);
    }
    // ---- per-lane constants ----
    v4f vb2[4]; // x TSCALE (C-init for scaled z2)
#pragma unroll
    for (int mt = 0; mt < 4; ++mt) {
        const int j0 = 16 * mt + 4 * q;
        vb2[mt][0] = TSCALE * b2[j0]; vb2[mt][1] = TSCALE * b2[j0 + 1];
        vb2[mt][2] = TSCALE * b2[j0 + 2]; vb2[mt][3] = TSCALE * b2[j0 + 3];
    }
    v4f vb3;
#pragma unroll
    for (int r = 0; r < 4; ++r) vb3[r] = b3[(4 * q + r) & 7];

    // ---- x state: ALL lanes hold xr[r] = x[row0+c][(4q+r)&7] (duplicated) ----
    float xr[4];
    {
        float4 v = *(const float4*)(x0 + (size_t)(row0 + c) * 8 + 4 * (q & 1));
        xr[0] = v.x; xr[1] = v.y; xr[2] = v.z; xr[3] = v.w;
    }
    const v4f vzero = {0.f, 0.f, 0.f, 0.f};
    v2f gv = {0.f, 0.f};

    // ================= iteration 0: pure forward at (x0, t=0) =================
    {
        FragU bx;
        bx.u[0] = pk16(xr[0], xr[1]);
        bx.u[1] = pk16(xr[2], xr[3]);
        bx.u[2] = pk16(0.0f, 1.0f);
        bx.u[3] = 0u;
        v4f d1[4];
#pragma unroll
        for (int mt = 0; mt < 4; ++mt)
            d1[mt] = __builtin_amdgcn_mfma_f32_16x16x32_f16(a1[mt].h, bx.h, vzero, 0, 0, 0);
        uint2 ph[4];
#pragma unroll
        for (int mt = 0; mt < 4; ++mt) {
            ph[mt].x = pk16(ftanh_s(d1[mt][0]), ftanh_s(d1[mt][1]));
            ph[mt].y = pk16(ftanh_s(d1[mt][2]), ftanh_s(d1[mt][3]));
        }
        FragU bh[2];
        rename(ph, bh);
        v4f d2[4];
#pragma unroll
        for (int mt = 0; mt < 4; ++mt) {
            d2[mt] = __builtin_amdgcn_mfma_f32_16x16x32_f16(a2[mt][0].h, bh[0].h, vb2[mt], 0, 0, 0);
            d2[mt] = __builtin_amdgcn_mfma_f32_16x16x32_f16(a2[mt][1].h, bh[1].h, d2[mt], 0, 0, 0);
        }
#pragma unroll
        for (int mt = 0; mt < 4; ++mt) {
            ph[mt].x = pk16(ftanh_s(d2[mt][0]), ftanh_s(d2[mt][1]));
            ph[mt].y = pk16(ftanh_s(d2[mt][2]), ftanh_s(d2[mt][3]));
        }
        FragU bh2[2];
        rename(ph, bh2);
        v4f d3;
        d3 = __builtin_amdgcn_mfma_f32_16x16x32_f16(a3[0].h, bh2[0].h, vb3, 0, 0, 0);
        d3 = __builtin_amdgcn_mfma_f32_16x16x32_f16(a3[1].h, bh2[1].h, d3, 0, 0, 0);
#pragma unroll
        for (int r = 0; r < 4; ++r) xr[r] = fmaf(dt, d3[r], xr[r]);
    }

    // ====== iterations i = 1..n-1: bwd(i-1) + fwd(i) from one L1 eval ======
    float tp = 0.0f; // t_{i-1}
    for (int i = 1; i < n; ++i) {
        FragU bx; // [x_i; t_{i-1}; 1]
        bx.u[0] = pk16(xr[0], xr[1]);
        bx.u[1] = pk16(xr[2], xr[3]);
        bx.u[2] = pk16(tp, 1.0f);
        bx.u[3] = 0u;
        tp += dt;
        v4f d1[4];
#pragma unroll
        for (int mt = 0; mt < 4; ++mt)
            d1[mt] = __builtin_amdgcn_mfma_f32_16x16x32_f16(a1[mt].h, bx.h, vzero, 0, 0, 0);

        // th1b = tanh(z1 @ t_{i-1}); om1 = 1 - th1b^2 in PACKED f16
        uint2 phb[4], pom[4];
#pragma unroll
        for (int mt = 0; mt < 4; ++mt) {
            phb[mt].x = pk16(ftanh_s(d1[mt][0]), ftanh_s(d1[mt][1]));
            phb[mt].y = pk16(ftanh_s(d1[mt][2]), ftanh_s(d1[mt][3]));
            pom[mt].x = pkom(phb[mt].x);
            pom[mt].y = pkom(phb[mt].y);
        }
        FragU bhb[2], bo[2];
        rename(phb, bhb);
        rename(pom, bo);

        v4f z2b[4], sg[4], dz2[4];
#pragma unroll
        for (int mt = 0; mt < 4; ++mt) {
            z2b[mt] = __builtin_amdgcn_mfma_f32_16x16x32_f16(a2[mt][0].h, bhb[0].h, vb2[mt], 0, 0, 0);
            z2b[mt] = __builtin_amdgcn_mfma_f32_16x16x32_f16(a2[mt][1].h, bhb[1].h, z2b[mt], 0, 0, 0);
            sg[mt] = __builtin_amdgcn_mfma_f32_16x16x32_f16(a2g[mt][0].h, bo[0].h, vzero, 0, 0, 0);
            sg[mt] = __builtin_amdgcn_mfma_f32_16x16x32_f16(a2g[mt][1].h, bo[1].h, sg[mt], 0, 0, 0);
            dz2[mt] = __builtin_amdgcn_mfma_f32_16x16x32_f16(a2d[mt][0].h, bo[0].h, vzero, 0, 0, 0);
            dz2[mt] = __builtin_amdgcn_mfma_f32_16x16x32_f16(a2d[mt][1].h, bo[1].h, dz2[mt], 0, 0, 0);
        }

        // th2b = tanh(z2b). g += om2*sg (w3c pre-folded). th2f = th2b+om2*dz2.
        uint2 ph2[4];
#pragma unroll
        for (int mt = 0; mt < 4; ++mt) {
            v2f th01 = {ftanh_s(z2b[mt][0]), ftanh_s(z2b[mt][1])};
            v2f th23 = {ftanh_s(z2b[mt][2]), ftanh_s(z2b[mt][3])};
            v2f om01 = v2f{1.f, 1.f} - th01 * th01;
            v2f om23 = v2f{1.f, 1.f} - th23 * th23;
            gv += om01 * v2f{sg[mt][0], sg[mt][1]};
            gv += om23 * v2f{sg[mt][2], sg[mt][3]};
            v2f tf01 = om01 * v2f{dz2[mt][0], dz2[mt][1]} + th01;
            v2f tf23 = om23 * v2f{dz2[mt][2], dz2[mt][3]} + th23;
            ph2[mt].x = pk16v(tf01);
            ph2[mt].y = pk16v(tf23);
        }
        FragU bh2[2];
        rename(ph2, bh2);
        v4f d3;
        d3 = __builtin_amdgcn_mfma_f32_16x16x32_f16(a3[0].h, bh2[0].h, vb3, 0, 0, 0);
        d3 = __builtin_amdgcn_mfma_f32_16x16x32_f16(a3[1].h, bh2[1].h, d3, 0, 0, 0);
#pragma unroll
        for (int r = 0; r < 4; ++r) xr[r] = fmaf(dt, d3[r], xr[r]);
    }

    // ============ final bwd at (x_n, t_{n-1}) ============
    {
        FragU bx;
        bx.u[0] = pk16(xr[0], xr[1]);
        bx.u[1] = pk16(xr[2], xr[3]);
        bx.u[2] = pk16(tp, 1.0f); // tp == (n-1)*dt
        bx.u[3] = 0u;
        v4f d1[4];
#pragma unroll
        for (int mt = 0; mt < 4; ++mt)
            d1[mt] = __builtin_amdgcn_mfma_f32_16x16x32_f16(a1[mt].h, bx.h, vzero, 0, 0, 0);
        uint2 phb[4], pom[4];
#pragma unroll
        for (int mt = 0; mt < 4; ++mt) {
            phb[mt].x = pk16(ftanh_s(d1[mt][0]), ftanh_s(d1[mt][1]));
            phb[mt].y = pk16(ftanh_s(d1[mt][2]), ftanh_s(d1[mt][3]));
            pom[mt].x = pkom(phb[mt].x);
            pom[mt].y = pkom(phb[mt].y);
        }
        FragU bhb[2], bo[2];
        rename(phb, bhb);
        rename(pom, bo);
        v4f z2b[4], sg[4];
#pragma unroll
        for (int mt = 0; mt < 4; ++mt) {
            z2b[mt] = __builtin_amdgcn_mfma_f32_16x16x32_f16(a2[mt][0].h, bhb[0].h, vb2[mt], 0, 0, 0);
            z2b[mt] = __builtin_amdgcn_mfma_f32_16x16x32_f16(a2[mt][1].h, bhb[1].h, z2b[mt], 0, 0, 0);
            sg[mt] = __builtin_amdgcn_mfma_f32_16x16x32_f16(a2g[mt][0].h, bo[0].h, vzero, 0, 0, 0);
            sg[mt] = __builtin_amdgcn_mfma_f32_16x16x32_f16(a2g[mt][1].h, bo[1].h, sg[mt], 0, 0, 0);
        }
#pragma unroll
        for (int mt = 0; mt < 4; ++mt) {
            v2f th01 = {ftanh_s(z2b[mt][0]), ftanh_s(z2b[mt][1])};
            v2f th23 = {ftanh_s(z2b[mt][2]), ftanh_s(z2b[mt][3])};
            v2f om01 = v2f{1.f, 1.f} - th01 * th01;
            v2f om23 = v2f{1.f, 1.f} - th23 * th23;
            gv += om01 * v2f{sg[mt][0], sg[mt][1]};
            gv += om23 * v2f{sg[mt][2], sg[mt][3]};
        }
    }

    // ---- epilogue ----
    float g = gv.x + gv.y;
    g += __shfl_xor(g, 16);
    g += __shfl_xor(g, 32);
    if (q < 2) {
        float4 st = {xr[0], xr[1], xr[2], xr[3]};
        *(float4*)(out + (size_t)(row0 + c) * 8 + 4 * q) = st;
    }
    if (q == 0) out[(size_t)rows * 8 + row0 + c] = dt * g;
}

extern "C" void kernel_launch(void* const* d_in, const int* in_sizes, int n_in,
                              void* d_out, int out_size, void* d_ws, size_t ws_size,
                              hipStream_t stream) {
    const float* x0 = (const float*)d_in[0];
    const float* W1 = (const float*)d_in[1];
    const float* b1 = (const float*)d_in[2];
    const float* W2 = (const float*)d_in[3];
    const float* b2 = (const float*)d_in[4];
    const float* W3 = (const float*)d_in[5];
    const float* b3 = (const float*)d_in[6];
    const int* ns = (const int*)d_in[7];
    float* out = (float*)d_out;
    const int rows = in_sizes[0] / 8; // 32768

    hipLaunchKernelGGL(cnf_fused, dim3(rows / 64), dim3(256), 0, stream,
                       x0, W1, b1, W2, b2, W3, b3, ns, out, rows);
}

// Round 5
// 185.097 us; speedup vs baseline: 5.7545x; 1.0507x over previous
//
#include <hip/hip_runtime.h>

// ContinuousNormalizingFlow: B=32768 rows, D=8, H=64, 100 Euler steps.
// R21: "s-form" tanh. R20 post-mortem confirmed the calibration: kernel is
// VALU-issue-bound at grid-capped 2 waves/SIMD; cutting ~32 f32 ops/iter
// gave -4.8%. This round cuts another 32 by quantizing s = 1/(exp2(z)+1)
// (3-op chain) instead of th = 1-2s (4-op chain) and folding the affine
// into MFMA constants (matrix pipe is 72% idle):
//   a2' = -2*TSCALE*W2, vb2' = TSCALE*(b2 + rowsum(W2))   [B-op = s1]
//   om/4 = s-s^2 packed f16 (1 pk_fma)                     [B-op = sigma1]
//   a2g' = 16*a2g, a2d' = 8*a2d  (exact scale absorption)
//   a3' = -2*W3, vb3' = b3 + rowsum(W3), B-op u = s2 - sigma2*dz2
// rowsums computed by setup MFMAs vs an all-ones B-frag (no load loops).
// Exact algebra; only change is f16-rounding s instead of th (<=2x abs
// err on B-operands; absmax is dominated by bx's f16(x), untouched).

#define TSCALE 2.885390081777926815f // 2*log2(e)

// s = 1/(2^z + 1)  (z pre-scaled by 2*log2e). th = 1-2s. inf-safe.
__device__ __forceinline__ float frcp3(float z) {
    float e = __builtin_amdgcn_exp2f(z);
    return __builtin_amdgcn_rcpf(e + 1.0f);
}

typedef __attribute__((ext_vector_type(8))) _Float16 v8h; // 8 f16 (4 VGPRs)
typedef __attribute__((ext_vector_type(2))) __fp16 v2fp; // cvt_pkrtz result
typedef __attribute__((ext_vector_type(4))) float v4f;   // MFMA C/D
typedef __attribute__((ext_vector_type(2))) float v2f;   // packed fp32 pair

union FragU {
    v8h h;
    unsigned u[4];
};

// f16 pair pack: single v_cvt_pkrtz_f16_f32. a -> low half.
__device__ __forceinline__ unsigned pk16(float a, float b) {
    v2fp t = __builtin_amdgcn_cvt_pkrtz(a, b);
    return __builtin_bit_cast(unsigned, t);
}
__device__ __forceinline__ unsigned pk16v(v2f v) { return pk16(v.x, v.y); }

// sigma = s - s^2 = om/4 on a packed f16 pair (one v_pk_fma_f16).
__device__ __forceinline__ unsigned pksig(unsigned sp) {
    v2fp s = __builtin_bit_cast(v2fp, sp);
    v2fp r = s - s * s;
    return __builtin_bit_cast(unsigned, r);
}

// K-permutation for W2/W3 frags: slot (ks,q,jj) <- physical j.
__device__ __forceinline__ int physj(int ks, int q, int jj) {
    return 16 * (ks + 2 * (jj >> 2)) + 4 * q + (jj & 3);
}

// Rename C-fragment packs (ph[4]: per-mt {r01,r23}) into the B-frag pair.
__device__ __forceinline__ void rename(const uint2 ph[4], FragU bh[2]) {
#pragma unroll
    for (int ks = 0; ks < 2; ++ks) {
        bh[ks].u[0] = ph[ks].x;
        bh[ks].u[1] = ph[ks].y;
        bh[ks].u[2] = ph[ks + 2].x;
        bh[ks].u[3] = ph[ks + 2].y;
    }
}

__global__ __launch_bounds__(256, 2) void cnf_fused(
    const float* __restrict__ x0, const float* __restrict__ W1,
    const float* __restrict__ b1, const float* __restrict__ W2,
    const float* __restrict__ b2, const float* __restrict__ W3,
    const float* __restrict__ b3, const int* __restrict__ nsp,
    float* __restrict__ out, int rows) {
    const int tid = threadIdx.x;
    const int w = tid >> 6;
    const int lane = tid & 63;
    const int c = lane & 15;
    const int q = lane >> 4;
    const int row0 = blockIdx.x * 64 + w * 16;

    const int n = *nsp;
    const float dt = 1.0f / (float)n;

    // ---- A1 (x TSCALE): [x;t;1] layout. q0 jj0-3 = W1[:,0:4], q0 jj4 =
    // W1[:,8] (t), q0 jj5 = b1, q1 jj0-3 = W1[:,4:8], all else 0. ----
    FragU a1[4];
#pragma unroll
    for (int mt = 0; mt < 4; ++mt) {
        const int m = 16 * mt + c;
        float f[8] = {0.f, 0.f, 0.f, 0.f, 0.f, 0.f, 0.f, 0.f};
        if (q == 0) {
#pragma unroll
            for (int jj = 0; jj < 4; ++jj) f[jj] = TSCALE * W1[m * 9 + jj];
            f[4] = TSCALE * W1[m * 9 + 8];
            f[5] = TSCALE * b1[m];
        } else if (q == 1) {
#pragma unroll
            for (int jj = 0; jj < 4; ++jj) f[jj] = TSCALE * W1[m * 9 + 4 + jj];
        }
#pragma unroll
        for (int p = 0; p < 4; ++p) a1[mt].u[p] = pk16(f[2 * p], f[2 * p + 1]);
    }
    // ---- A2 (x -2*TSCALE, s-form) K-perm; a2g = 16*w3c*W2*w1r (B-op =
    // sigma1 = om1/4); a2d = 8*W2*(dt*w1t) (B-op = sigma1, output 2*dz2).
    FragU a2[4][2], a2g[4][2], a2d[4][2];
#pragma unroll
    for (int mt = 0; mt < 4; ++mt) {
        const int m = 16 * mt + c;
        float w3cm = 0.f;
#pragma unroll
        for (int d = 0; d < 8; ++d) w3cm += W3[d * 64 + m];
#pragma unroll
        for (int ks = 0; ks < 2; ++ks) {
            float f[8], fg[8], fd[8];
#pragma unroll
            for (int jj = 0; jj < 8; ++jj) {
                const int pj = physj(ks, q, jj);
                const float wv = W2[m * 64 + pj];
                float w1r = 0.f;
#pragma unroll
                for (int k = 0; k < 8; ++k) w1r += W1[pj * 9 + k];
                f[jj] = -2.0f * TSCALE * wv;
                fg[jj] = 16.0f * w3cm * wv * w1r;
                fd[jj] = 8.0f * wv * (dt * W1[pj * 9 + 8]);
            }
#pragma unroll
            for (int p = 0; p < 4; ++p) {
                a2[mt][ks].u[p] = pk16(f[2 * p], f[2 * p + 1]);
                a2g[mt][ks].u[p] = pk16(fg[2 * p], fg[2 * p + 1]);
                a2d[mt][ks].u[p] = pk16(fd[2 * p], fd[2 * p + 1]);
            }
        }
    }
    // ---- A3 (x -2, s-form): W3 rows duplicated (m -> m&7), K-permuted ----
    FragU a3[2];
#pragma unroll
    for (int ks = 0; ks < 2; ++ks) {
        float f[8];
#pragma unroll
        for (int jj = 0; jj < 8; ++jj)
            f[jj] = -2.0f * W3[(c & 7) * 64 + physj(ks, q, jj)];
#pragma unroll
        for (int p = 0; p < 4; ++p) a3[ks].u[p] = pk16(f[2 * p], f[2 * p + 1]);
    }

    const v4f vzero = {0.f, 0.f, 0.f, 0.f};
    // ---- all-ones B-frag for setup rowsum MFMAs ----
    FragU ones;
    ones.u[0] = ones.u[1] = ones.u[2] = ones.u[3] = 0x3C003C00u;

    // ---- vb2 = TSCALE*(b2 + rowsum(W2)) via a2*ones (a2 = -2*TS*W2) ----
    v4f vb2[4];
#pragma unroll
    for (int mt = 0; mt < 4; ++mt) {
        v4f t = __builtin_amdgcn_mfma_f32_16x16x32_f16(a2[mt][0].h, ones.h, vzero, 0, 0, 0);
        t = __builtin_amdgcn_mfma_f32_16x16x32_f16(a2[mt][1].h, ones.h, t, 0, 0, 0);
        const int j0 = 16 * mt + 4 * q;
#pragma unroll
        for (int r = 0; r < 4; ++r)
            vb2[mt][r] = TSCALE * b2[j0 + r] - 0.5f * t[r];
    }
    // ---- vb3 = b3 + rowsum(W3) via a3*ones (a3 = -2*W3) ----
    v4f vb3;
    {
        v4f t = __builtin_amdgcn_mfma_f32_16x16x32_f16(a3[0].h, ones.h, vzero, 0, 0, 0);
        t = __builtin_amdgcn_mfma_f32_16x16x32_f16(a3[1].h, ones.h, t, 0, 0, 0);
#pragma unroll
        for (int r = 0; r < 4; ++r) vb3[r] = b3[(4 * q + r) & 7] - 0.5f * t[r];
    }

    // ---- x state: ALL lanes hold xr[r] = x[row0+c][(4q+r)&7] (duplicated) ----
    float xr[4];
    {
        float4 v = *(const float4*)(x0 + (size_t)(row0 + c) * 8 + 4 * (q & 1));
        xr[0] = v.x; xr[1] = v.y; xr[2] = v.z; xr[3] = v.w;
    }
    v2f gv = {0.f, 0.f};

    // ================= iteration 0: pure forward at (x0, t=0) =================
    {
        FragU bx;
        bx.u[0] = pk16(xr[0], xr[1]);
        bx.u[1] = pk16(xr[2], xr[3]);
        bx.u[2] = pk16(0.0f, 1.0f);
        bx.u[3] = 0u;
        v4f d1[4];
#pragma unroll
        for (int mt = 0; mt < 4; ++mt)
            d1[mt] = __builtin_amdgcn_mfma_f32_16x16x32_f16(a1[mt].h, bx.h, vzero, 0, 0, 0);
        uint2 ps[4];
#pragma unroll
        for (int mt = 0; mt < 4; ++mt) {
            ps[mt].x = pk16(frcp3(d1[mt][0]), frcp3(d1[mt][1]));
            ps[mt].y = pk16(frcp3(d1[mt][2]), frcp3(d1[mt][3]));
        }
        FragU bs[2];
        rename(ps, bs);
        v4f d2[4];
#pragma unroll
        for (int mt = 0; mt < 4; ++mt) {
            d2[mt] = __builtin_amdgcn_mfma_f32_16x16x32_f16(a2[mt][0].h, bs[0].h, vb2[mt], 0, 0, 0);
            d2[mt] = __builtin_amdgcn_mfma_f32_16x16x32_f16(a2[mt][1].h, bs[1].h, d2[mt], 0, 0, 0);
        }
#pragma unroll
        for (int mt = 0; mt < 4; ++mt) {
            ps[mt].x = pk16(frcp3(d2[mt][0]), frcp3(d2[mt][1]));
            ps[mt].y = pk16(frcp3(d2[mt][2]), frcp3(d2[mt][3]));
        }
        FragU bs2[2];
        rename(ps, bs2);
        v4f d3;
        d3 = __builtin_amdgcn_mfma_f32_16x16x32_f16(a3[0].h, bs2[0].h, vb3, 0, 0, 0);
        d3 = __builtin_amdgcn_mfma_f32_16x16x32_f16(a3[1].h, bs2[1].h, d3, 0, 0, 0);
#pragma unroll
        for (int r = 0; r < 4; ++r) xr[r] = fmaf(dt, d3[r], xr[r]);
    }

    // ====== iterations i = 1..n-1: bwd(i-1) + fwd(i) from one L1 eval ======
    float tp = 0.0f; // t_{i-1}
    for (int i = 1; i < n; ++i) {
        FragU bx; // [x_i; t_{i-1}; 1]
        bx.u[0] = pk16(xr[0], xr[1]);
        bx.u[1] = pk16(xr[2], xr[3]);
        bx.u[2] = pk16(tp, 1.0f);
        bx.u[3] = 0u;
        tp += dt;
        v4f d1[4];
#pragma unroll
        for (int mt = 0; mt < 4; ++mt)
            d1[mt] = __builtin_amdgcn_mfma_f32_16x16x32_f16(a1[mt].h, bx.h, vzero, 0, 0, 0);

        // layer 1: s1 packed (3-op chains); sigma1 = s1 - s1^2 packed f16
        uint2 psb[4], psg[4];
#pragma unroll
        for (int mt = 0; mt < 4; ++mt) {
            psb[mt].x = pk16(frcp3(d1[mt][0]), frcp3(d1[mt][1]));
            psb[mt].y = pk16(frcp3(d1[mt][2]), frcp3(d1[mt][3]));
            psg[mt].x = pksig(psb[mt].x);
            psg[mt].y = pksig(psb[mt].y);
        }
        FragU bs[2], bo[2];
        rename(psb, bs);
        rename(psg, bo);

        v4f z2b[4], sg[4], dz2[4];
#pragma unroll
        for (int mt = 0; mt < 4; ++mt) {
            z2b[mt] = __builtin_amdgcn_mfma_f32_16x16x32_f16(a2[mt][0].h, bs[0].h, vb2[mt], 0, 0, 0);
            z2b[mt] = __builtin_amdgcn_mfma_f32_16x16x32_f16(a2[mt][1].h, bs[1].h, z2b[mt], 0, 0, 0);
            sg[mt] = __builtin_amdgcn_mfma_f32_16x16x32_f16(a2g[mt][0].h, bo[0].h, vzero, 0, 0, 0);
            sg[mt] = __builtin_amdgcn_mfma_f32_16x16x32_f16(a2g[mt][1].h, bo[1].h, sg[mt], 0, 0, 0);
            dz2[mt] = __builtin_amdgcn_mfma_f32_16x16x32_f16(a2d[mt][0].h, bo[0].h, vzero, 0, 0, 0);
            dz2[mt] = __builtin_amdgcn_mfma_f32_16x16x32_f16(a2d[mt][1].h, bo[1].h, dz2[mt], 0, 0, 0);
        }

        // layer 2: s2 (3-op); sigma2 = s2-s2^2; gv += sigma2*sg;
        // u = s2 - sigma2*dz2  (d3 B-operand; tf = 1-2u exactly)
        uint2 pu[4];
#pragma unroll
        for (int mt = 0; mt < 4; ++mt) {
            v2f s01 = {frcp3(z2b[mt][0]), frcp3(z2b[mt][1])};
            v2f s23 = {frcp3(z2b[mt][2]), frcp3(z2b[mt][3])};
            v2f g01 = s01 - s01 * s01;
            v2f g23 = s23 - s23 * s23;
            gv += g01 * v2f{sg[mt][0], sg[mt][1]};
            gv += g23 * v2f{sg[mt][2], sg[mt][3]};
            v2f u01 = s01 - g01 * v2f{dz2[mt][0], dz2[mt][1]};
            v2f u23 = s23 - g23 * v2f{dz2[mt][2], dz2[mt][3]};
            pu[mt].x = pk16v(u01);
            pu[mt].y = pk16v(u23);
        }
        FragU bu[2];
        rename(pu, bu);
        v4f d3;
        d3 = __builtin_amdgcn_mfma_f32_16x16x32_f16(a3[0].h, bu[0].h, vb3, 0, 0, 0);
        d3 = __builtin_amdgcn_mfma_f32_16x16x32_f16(a3[1].h, bu[1].h, d3, 0, 0, 0);
#pragma unroll
        for (int r = 0; r < 4; ++r) xr[r] = fmaf(dt, d3[r], xr[r]);
    }

    // ============ final bwd at (x_n, t_{n-1}) ============
    {
        FragU bx;
        bx.u[0] = pk16(xr[0], xr[1]);
        bx.u[1] = pk16(xr[2], xr[3]);
        bx.u[2] = pk16(tp, 1.0f); // tp == (n-1)*dt
        bx.u[3] = 0u;
        v4f d1[4];
#pragma unroll
        for (int mt = 0; mt < 4; ++mt)
            d1[mt] = __builtin_amdgcn_mfma_f32_16x16x32_f16(a1[mt].h, bx.h, vzero, 0, 0, 0);
        uint2 psb[4], psg[4];
#pragma unroll
        for (int mt = 0; mt < 4; ++mt) {
            psb[mt].x = pk16(frcp3(d1[mt][0]), frcp3(d1[mt][1]));
            psb[mt].y = pk16(frcp3(d1[mt][2]), frcp3(d1[mt][3]));
            psg[mt].x = pksig(psb[mt].x);
            psg[mt].y = pksig(psb[mt].y);
        }
        FragU bs[2], bo[2];
        rename(psb, bs);
        rename(psg, bo);
        v4f z2b[4], sg[4];
#pragma unroll
        for (int mt = 0; mt < 4; ++mt) {
            z2b[mt] = __builtin_amdgcn_mfma_f32_16x16x32_f16(a2[mt][0].h, bs[0].h, vb2[mt], 0, 0, 0);
            z2b[mt] = __builtin_amdgcn_mfma_f32_16x16x32_f16(a2[mt][1].h, bs[1].h, z2b[mt], 0, 0, 0);
            sg[mt] = __builtin_amdgcn_mfma_f32_16x16x32_f16(a2g[mt][0].h, bo[0].h, vzero, 0, 0, 0);
            sg[mt] = __builtin_amdgcn_mfma_f32_16x16x32_f16(a2g[mt][1].h, bo[1].h, sg[mt], 0, 0, 0);
        }
#pragma unroll
        for (int mt = 0; mt < 4; ++mt) {
            v2f s01 = {frcp3(z2b[mt][0]), frcp3(z2b[mt][1])};
            v2f s23 = {frcp3(z2b[mt][2]), frcp3(z2b[mt][3])};
            v2f g01 = s01 - s01 * s01;
            v2f g23 = s23 - s23 * s23;
            gv += g01 * v2f{sg[mt][0], sg[mt][1]};
            gv += g23 * v2f{sg[mt][2], sg[mt][3]};
        }
    }

    // ---- epilogue ----
    float g = gv.x + gv.y;
    g += __shfl_xor(g, 16);
    g += __shfl_xor(g, 32);
    if (q < 2) {
        float4 st = {xr[0], xr[1], xr[2], xr[3]};
        *(float4*)(out + (size_t)(row0 + c) * 8 + 4 * q) = st;
    }
    if (q == 0) out[(size_t)rows * 8 + row0 + c] = dt * g;
}

extern "C" void kernel_launch(void* const* d_in, const int* in_sizes, int n_in,
                              void* d_out, int out_size, void* d_ws, size_t ws_size,
                              hipStream_t stream) {
    const float* x0 = (const float*)d_in[0];
    const float* W1 = (const float*)d_in[1];
    const float* b1 = (const float*)d_in[2];
    const float* W2 = (const float*)d_in[3];
    const float* b2 = (const float*)d_in[4];
    const float* W3 = (const float*)d_in[5];
    const float* b3 = (const float*)d_in[6];
    const int* ns = (const int*)d_in[7];
    float* out = (float*)d_out;
    const int rows = in_sizes[0] / 8; // 32768

    hipLaunchKernelGGL(cnf_fused, dim3(rows / 64), dim3(256), 0, stream,
                       x0, W1, b1, W2, b2, W3, b3, ns, out, rows);
}

// Round 6
// 183.952 us; speedup vs baseline: 5.7904x; 1.0062x over previous
//
#include <hip/hip_runtime.h>

// ContinuousNormalizingFlow: B=32768 rows, D=8, H=64, 100 Euler steps.
// R22: cross-iteration software pipeline. R21 audit: per-wave issue count
// (~190 inst/iter) is far below the measured ~3400 cyc/iter/SIMD wall ->
// the kernel is dependency-LATENCY dominated (serial chain d1->trans->
// z2b->trans->u->d3->xr with MFMA-result hazards), and the 2 grid-capped
// resident waves only partially cover each other. The bwd/logdet work
// (8 sg MFMAs + gv dot) is off the critical path but the compiler can't
// move it across the loop back-edge. Change: defer iteration i's sg/gv to
// iteration i+1, issued right after d1 (filling the d1->frcp3 latency
// hole). Same total ops (+8 one-time A2g*0 MFMAs), identical numerics
// (same values, same gv accumulation order, issued one iter later).
// Everything else is R21 exactly (s-form tanh, folded scales).

#define TSCALE 2.885390081777926815f // 2*log2(e)

// s = 1/(2^z + 1)  (z pre-scaled by 2*log2e). th = 1-2s. inf-safe.
__device__ __forceinline__ float frcp3(float z) {
    float e = __builtin_amdgcn_exp2f(z);
    return __builtin_amdgcn_rcpf(e + 1.0f);
}

typedef __attribute__((ext_vector_type(8))) _Float16 v8h; // 8 f16 (4 VGPRs)
typedef __attribute__((ext_vector_type(2))) __fp16 v2fp; // cvt_pkrtz result
typedef __attribute__((ext_vector_type(4))) float v4f;   // MFMA C/D
typedef __attribute__((ext_vector_type(2))) float v2f;   // packed fp32 pair

union FragU {
    v8h h;
    unsigned u[4];
};

// f16 pair pack: single v_cvt_pkrtz_f16_f32. a -> low half.
__device__ __forceinline__ unsigned pk16(float a, float b) {
    v2fp t = __builtin_amdgcn_cvt_pkrtz(a, b);
    return __builtin_bit_cast(unsigned, t);
}
__device__ __forceinline__ unsigned pk16v(v2f v) { return pk16(v.x, v.y); }

// sigma = s - s^2 = om/4 on a packed f16 pair (one v_pk_fma_f16).
__device__ __forceinline__ unsigned pksig(unsigned sp) {
    v2fp s = __builtin_bit_cast(v2fp, sp);
    v2fp r = s - s * s;
    return __builtin_bit_cast(unsigned, r);
}

// K-permutation for W2/W3 frags: slot (ks,q,jj) <- physical j.
__device__ __forceinline__ int physj(int ks, int q, int jj) {
    return 16 * (ks + 2 * (jj >> 2)) + 4 * q + (jj & 3);
}

// Rename C-fragment packs (ph[4]: per-mt {r01,r23}) into the B-frag pair.
__device__ __forceinline__ void rename(const uint2 ph[4], FragU bh[2]) {
#pragma unroll
    for (int ks = 0; ks < 2; ++ks) {
        bh[ks].u[0] = ph[ks].x;
        bh[ks].u[1] = ph[ks].y;
        bh[ks].u[2] = ph[ks + 2].x;
        bh[ks].u[3] = ph[ks + 2].y;
    }
}

__global__ __launch_bounds__(256, 2) void cnf_fused(
    const float* __restrict__ x0, const float* __restrict__ W1,
    const float* __restrict__ b1, const float* __restrict__ W2,
    const float* __restrict__ b2, const float* __restrict__ W3,
    const float* __restrict__ b3, const int* __restrict__ nsp,
    float* __restrict__ out, int rows) {
    const int tid = threadIdx.x;
    const int w = tid >> 6;
    const int lane = tid & 63;
    const int c = lane & 15;
    const int q = lane >> 4;
    const int row0 = blockIdx.x * 64 + w * 16;

    const int n = *nsp;
    const float dt = 1.0f / (float)n;

    // ---- A1 (x TSCALE): [x;t;1] layout. q0 jj0-3 = W1[:,0:4], q0 jj4 =
    // W1[:,8] (t), q0 jj5 = b1, q1 jj0-3 = W1[:,4:8], all else 0. ----
    FragU a1[4];
#pragma unroll
    for (int mt = 0; mt < 4; ++mt) {
        const int m = 16 * mt + c;
        float f[8] = {0.f, 0.f, 0.f, 0.f, 0.f, 0.f, 0.f, 0.f};
        if (q == 0) {
#pragma unroll
            for (int jj = 0; jj < 4; ++jj) f[jj] = TSCALE * W1[m * 9 + jj];
            f[4] = TSCALE * W1[m * 9 + 8];
            f[5] = TSCALE * b1[m];
        } else if (q == 1) {
#pragma unroll
            for (int jj = 0; jj < 4; ++jj) f[jj] = TSCALE * W1[m * 9 + 4 + jj];
        }
#pragma unroll
        for (int p = 0; p < 4; ++p) a1[mt].u[p] = pk16(f[2 * p], f[2 * p + 1]);
    }
    // ---- A2 (x -2*TSCALE, s-form) K-perm; a2g = 16*w3c*W2*w1r (B-op =
    // sigma1 = om1/4); a2d = 8*W2*(dt*w1t) (B-op = sigma1, output 2*dz2).
    FragU a2[4][2], a2g[4][2], a2d[4][2];
#pragma unroll
    for (int mt = 0; mt < 4; ++mt) {
        const int m = 16 * mt + c;
        float w3cm = 0.f;
#pragma unroll
        for (int d = 0; d < 8; ++d) w3cm += W3[d * 64 + m];
#pragma unroll
        for (int ks = 0; ks < 2; ++ks) {
            float f[8], fg[8], fd[8];
#pragma unroll
            for (int jj = 0; jj < 8; ++jj) {
                const int pj = physj(ks, q, jj);
                const float wv = W2[m * 64 + pj];
                float w1r = 0.f;
#pragma unroll
                for (int k = 0; k < 8; ++k) w1r += W1[pj * 9 + k];
                f[jj] = -2.0f * TSCALE * wv;
                fg[jj] = 16.0f * w3cm * wv * w1r;
                fd[jj] = 8.0f * wv * (dt * W1[pj * 9 + 8]);
            }
#pragma unroll
            for (int p = 0; p < 4; ++p) {
                a2[mt][ks].u[p] = pk16(f[2 * p], f[2 * p + 1]);
                a2g[mt][ks].u[p] = pk16(fg[2 * p], fg[2 * p + 1]);
                a2d[mt][ks].u[p] = pk16(fd[2 * p], fd[2 * p + 1]);
            }
        }
    }
    // ---- A3 (x -2, s-form): W3 rows duplicated (m -> m&7), K-permuted ----
    FragU a3[2];
#pragma unroll
    for (int ks = 0; ks < 2; ++ks) {
        float f[8];
#pragma unroll
        for (int jj = 0; jj < 8; ++jj)
            f[jj] = -2.0f * W3[(c & 7) * 64 + physj(ks, q, jj)];
#pragma unroll
        for (int p = 0; p < 4; ++p) a3[ks].u[p] = pk16(f[2 * p], f[2 * p + 1]);
    }

    const v4f vzero = {0.f, 0.f, 0.f, 0.f};
    // ---- all-ones B-frag for setup rowsum MFMAs ----
    FragU ones;
    ones.u[0] = ones.u[1] = ones.u[2] = ones.u[3] = 0x3C003C00u;

    // ---- vb2 = TSCALE*(b2 + rowsum(W2)) via a2*ones (a2 = -2*TS*W2) ----
    v4f vb2[4];
#pragma unroll
    for (int mt = 0; mt < 4; ++mt) {
        v4f t = __builtin_amdgcn_mfma_f32_16x16x32_f16(a2[mt][0].h, ones.h, vzero, 0, 0, 0);
        t = __builtin_amdgcn_mfma_f32_16x16x32_f16(a2[mt][1].h, ones.h, t, 0, 0, 0);
        const int j0 = 16 * mt + 4 * q;
#pragma unroll
        for (int r = 0; r < 4; ++r)
            vb2[mt][r] = TSCALE * b2[j0 + r] - 0.5f * t[r];
    }
    // ---- vb3 = b3 + rowsum(W3) via a3*ones (a3 = -2*W3) ----
    v4f vb3;
    {
        v4f t = __builtin_amdgcn_mfma_f32_16x16x32_f16(a3[0].h, ones.h, vzero, 0, 0, 0);
        t = __builtin_amdgcn_mfma_f32_16x16x32_f16(a3[1].h, ones.h, t, 0, 0, 0);
#pragma unroll
        for (int r = 0; r < 4; ++r) vb3[r] = b3[(4 * q + r) & 7] - 0.5f * t[r];
    }

    // ---- x state: ALL lanes hold xr[r] = x[row0+c][(4q+r)&7] (duplicated) ----
    float xr[4];
    {
        float4 v = *(const float4*)(x0 + (size_t)(row0 + c) * 8 + 4 * (q & 1));
        xr[0] = v.x; xr[1] = v.y; xr[2] = v.z; xr[3] = v.w;
    }
    v2f gv = {0.f, 0.f};

    // ================= iteration 0: pure forward at (x0, t=0) =================
    {
        FragU bx;
        bx.u[0] = pk16(xr[0], xr[1]);
        bx.u[1] = pk16(xr[2], xr[3]);
        bx.u[2] = pk16(0.0f, 1.0f);
        bx.u[3] = 0u;
        v4f d1[4];
#pragma unroll
        for (int mt = 0; mt < 4; ++mt)
            d1[mt] = __builtin_amdgcn_mfma_f32_16x16x32_f16(a1[mt].h, bx.h, vzero, 0, 0, 0);
        uint2 ps[4];
#pragma unroll
        for (int mt = 0; mt < 4; ++mt) {
            ps[mt].x = pk16(frcp3(d1[mt][0]), frcp3(d1[mt][1]));
            ps[mt].y = pk16(frcp3(d1[mt][2]), frcp3(d1[mt][3]));
        }
        FragU bs[2];
        rename(ps, bs);
        v4f d2[4];
#pragma unroll
        for (int mt = 0; mt < 4; ++mt) {
            d2[mt] = __builtin_amdgcn_mfma_f32_16x16x32_f16(a2[mt][0].h, bs[0].h, vb2[mt], 0, 0, 0);
            d2[mt] = __builtin_amdgcn_mfma_f32_16x16x32_f16(a2[mt][1].h, bs[1].h, d2[mt], 0, 0, 0);
        }
#pragma unroll
        for (int mt = 0; mt < 4; ++mt) {
            ps[mt].x = pk16(frcp3(d2[mt][0]), frcp3(d2[mt][1]));
            ps[mt].y = pk16(frcp3(d2[mt][2]), frcp3(d2[mt][3]));
        }
        FragU bs2[2];
        rename(ps, bs2);
        v4f d3;
        d3 = __builtin_amdgcn_mfma_f32_16x16x32_f16(a3[0].h, bs2[0].h, vb3, 0, 0, 0);
        d3 = __builtin_amdgcn_mfma_f32_16x16x32_f16(a3[1].h, bs2[1].h, d3, 0, 0, 0);
#pragma unroll
        for (int r = 0; r < 4; ++r) xr[r] = fmaf(dt, d3[r], xr[r]);
    }

    // ---- deferred-bwd pipeline state: sigma1 frags + sigma2 (f32) of the
    // previous loop iteration. Zero-init => first pass does A2g*0 (no-op). ----
    FragU boP[2];
    boP[0].u[0] = boP[0].u[1] = boP[0].u[2] = boP[0].u[3] = 0u;
    boP[1].u[0] = boP[1].u[1] = boP[1].u[2] = boP[1].u[3] = 0u;
    v2f gp01[4], gp23[4];
#pragma unroll
    for (int mt = 0; mt < 4; ++mt) {
        gp01[mt] = v2f{0.f, 0.f};
        gp23[mt] = v2f{0.f, 0.f};
    }

    // ====== iterations i = 1..n-1: bwd(i-1) + fwd(i) from one L1 eval;
    // the sg/gv (logdet) part of bwd(i-1) is deferred into iteration i ======
    float tp = 0.0f; // t_{i-1}
    for (int i = 1; i < n; ++i) {
        FragU bx; // [x_i; t_{i-1}; 1]
        bx.u[0] = pk16(xr[0], xr[1]);
        bx.u[1] = pk16(xr[2], xr[3]);
        bx.u[2] = pk16(tp, 1.0f);
        bx.u[3] = 0u;
        tp += dt;
        v4f d1[4];
#pragma unroll
        for (int mt = 0; mt < 4; ++mt)
            d1[mt] = __builtin_amdgcn_mfma_f32_16x16x32_f16(a1[mt].h, bx.h, vzero, 0, 0, 0);

        // ---- deferred sg/gv of PREVIOUS iteration: fills d1's latency ----
#pragma unroll
        for (int mt = 0; mt < 4; ++mt) {
            v4f sgp = __builtin_amdgcn_mfma_f32_16x16x32_f16(a2g[mt][0].h, boP[0].h, vzero, 0, 0, 0);
            sgp = __builtin_amdgcn_mfma_f32_16x16x32_f16(a2g[mt][1].h, boP[1].h, sgp, 0, 0, 0);
            gv += gp01[mt] * v2f{sgp[0], sgp[1]};
            gv += gp23[mt] * v2f{sgp[2], sgp[3]};
        }

        // layer 1: s1 packed (3-op chains); sigma1 = s1 - s1^2 packed f16
        uint2 psb[4], psg[4];
#pragma unroll
        for (int mt = 0; mt < 4; ++mt) {
            psb[mt].x = pk16(frcp3(d1[mt][0]), frcp3(d1[mt][1]));
            psb[mt].y = pk16(frcp3(d1[mt][2]), frcp3(d1[mt][3]));
            psg[mt].x = pksig(psb[mt].x);
            psg[mt].y = pksig(psb[mt].y);
        }
        FragU bs[2];
        rename(psb, bs);
        rename(psg, boP); // overwrite pipeline state (deferred block read it)

        v4f z2b[4], dz2[4];
#pragma unroll
        for (int mt = 0; mt < 4; ++mt) {
            z2b[mt] = __builtin_amdgcn_mfma_f32_16x16x32_f16(a2[mt][0].h, bs[0].h, vb2[mt], 0, 0, 0);
            z2b[mt] = __builtin_amdgcn_mfma_f32_16x16x32_f16(a2[mt][1].h, bs[1].h, z2b[mt], 0, 0, 0);
            dz2[mt] = __builtin_amdgcn_mfma_f32_16x16x32_f16(a2d[mt][0].h, boP[0].h, vzero, 0, 0, 0);
            dz2[mt] = __builtin_amdgcn_mfma_f32_16x16x32_f16(a2d[mt][1].h, boP[1].h, dz2[mt], 0, 0, 0);
        }

        // layer 2: s2 (3-op); sigma2 = s2-s2^2 (saved for deferred gv);
        // u = s2 - sigma2*dz2  (d3 B-operand; tf = 1-2u exactly)
        uint2 pu[4];
#pragma unroll
        for (int mt = 0; mt < 4; ++mt) {
            v2f s01 = {frcp3(z2b[mt][0]), frcp3(z2b[mt][1])};
            v2f s23 = {frcp3(z2b[mt][2]), frcp3(z2b[mt][3])};
            v2f g01 = s01 - s01 * s01;
            v2f g23 = s23 - s23 * s23;
            gp01[mt] = g01;
            gp23[mt] = g23;
            v2f u01 = s01 - g01 * v2f{dz2[mt][0], dz2[mt][1]};
            v2f u23 = s23 - g23 * v2f{dz2[mt][2], dz2[mt][3]};
            pu[mt].x = pk16v(u01);
            pu[mt].y = pk16v(u23);
        }
        FragU bu[2];
        rename(pu, bu);
        v4f d3;
        d3 = __builtin_amdgcn_mfma_f32_16x16x32_f16(a3[0].h, bu[0].h, vb3, 0, 0, 0);
        d3 = __builtin_amdgcn_mfma_f32_16x16x32_f16(a3[1].h, bu[1].h, d3, 0, 0, 0);
#pragma unroll
        for (int r = 0; r < 4; ++r) xr[r] = fmaf(dt, d3[r], xr[r]);
    }

    // ---- flush deferred sg/gv of the last loop iteration ----
#pragma unroll
    for (int mt = 0; mt < 4; ++mt) {
        v4f sgp = __builtin_amdgcn_mfma_f32_16x16x32_f16(a2g[mt][0].h, boP[0].h, vzero, 0, 0, 0);
        sgp = __builtin_amdgcn_mfma_f32_16x16x32_f16(a2g[mt][1].h, boP[1].h, sgp, 0, 0, 0);
        gv += gp01[mt] * v2f{sgp[0], sgp[1]};
        gv += gp23[mt] * v2f{sgp[2], sgp[3]};
    }

    // ============ final bwd at (x_n, t_{n-1}) ============
    {
        FragU bx;
        bx.u[0] = pk16(xr[0], xr[1]);
        bx.u[1] = pk16(xr[2], xr[3]);
        bx.u[2] = pk16(tp, 1.0f); // tp == (n-1)*dt
        bx.u[3] = 0u;
        v4f d1[4];
#pragma unroll
        for (int mt = 0; mt < 4; ++mt)
            d1[mt] = __builtin_amdgcn_mfma_f32_16x16x32_f16(a1[mt].h, bx.h, vzero, 0, 0, 0);
        uint2 psb[4], psg[4];
#pragma unroll
        for (int mt = 0; mt < 4; ++mt) {
            psb[mt].x = pk16(frcp3(d1[mt][0]), frcp3(d1[mt][1]));
            psb[mt].y = pk16(frcp3(d1[mt][2]), frcp3(d1[mt][3]));
            psg[mt].x = pksig(psb[mt].x);
            psg[mt].y = pksig(psb[mt].y);
        }
        FragU bs[2], bo[2];
        rename(psb, bs);
        rename(psg, bo);
        v4f z2b[4], sg[4];
#pragma unroll
        for (int mt = 0; mt < 4; ++mt) {
            z2b[mt] = __builtin_amdgcn_mfma_f32_16x16x32_f16(a2[mt][0].h, bs[0].h, vb2[mt], 0, 0, 0);
            z2b[mt] = __builtin_amdgcn_mfma_f32_16x16x32_f16(a2[mt][1].h, bs[1].h, z2b[mt], 0, 0, 0);
            sg[mt] = __builtin_amdgcn_mfma_f32_16x16x32_f16(a2g[mt][0].h, bo[0].h, vzero, 0, 0, 0);
            sg[mt] = __builtin_amdgcn_mfma_f32_16x16x32_f16(a2g[mt][1].h, bo[1].h, sg[mt], 0, 0, 0);
        }
#pragma unroll
        for (int mt = 0; mt < 4; ++mt) {
            v2f s01 = {frcp3(z2b[mt][0]), frcp3(z2b[mt][1])};
            v2f s23 = {frcp3(z2b[mt][2]), frcp3(z2b[mt][3])};
            v2f g01 = s01 - s01 * s01;
            v2f g23 = s23 - s23 * s23;
            gv += g01 * v2f{sg[mt][0], sg[mt][1]};
            gv += g23 * v2f{sg[mt][2], sg[mt][3]};
        }
    }

    // ---- epilogue ----
    float g = gv.x + gv.y;
    g += __shfl_xor(g, 16);
    g += __shfl_xor(g, 32);
    if (q < 2) {
        float4 st = {xr[0], xr[1], xr[2], xr[3]};
        *(float4*)(out + (size_t)(row0 + c) * 8 + 4 * q) = st;
    }
    if (q == 0) out[(size_t)rows * 8 + row0 + c] = dt * g;
}

extern "C" void kernel_launch(void* const* d_in, const int* in_sizes, int n_in,
                              void* d_out, int out_size, void* d_ws, size_t ws_size,
                              hipStream_t stream) {
    const float* x0 = (const float*)d_in[0];
    const float* W1 = (const float*)d_in[1];
    const float* b1 = (const float*)d_in[2];
    const float* W2 = (const float*)d_in[3];
    const float* b2 = (const float*)d_in[4];
    const float* W3 = (const float*)d_in[5];
    const float* b3 = (const float*)d_in[6];
    const int* ns = (const int*)d_in[7];
    float* out = (float*)d_out;
    const int rows = in_sizes[0] / 8; // 32768

    hipLaunchKernelGGL(cnf_fused, dim3(rows / 64), dim3(256), 0, stream,
                       x0, W1, b1, W2, b2, W3, b3, ns, out, rows);
}